// Round 1
// baseline (81562.341 us; speedup 1.0000x reference)
//
#include <hip/hip_runtime.h>
#include <math.h>

// ===== jax threefry mode: 1 = partitionable (jax >= 0.4.36 default) =====
#define JAX_PARTITIONABLE 1

// ---- model dims: NL=6 D=256 FF=1024 V=1024 S=48 BS=64 H=8 DH=32 ----

// ---- workspace layout (float offsets) ----
// Transposed decode weights (built after encoder; region doubles as X/MEM during encoder)
static constexpr int SWQKVT  = 0;                        // 6 x [256 k][768 o]
static constexpr int SWOT    = SWQKVT + 6*256*768;       // 1,179,648 ; 6 x [256][256]
static constexpr int CWQT    = SWOT   + 6*256*256;       // 1,572,864
static constexpr int CWOT    = CWQT   + 6*256*256;       // 1,966,080
static constexpr int DW1T    = CWOT   + 6*256*256;       // 2,359,296 ; 6 x [256][1024]
static constexpr int DW2T    = DW1T   + 6*256*1024;      // 3,932,160 ; 6 x [1024][256]
static constexpr int WT_END  = DW2T   + 6*1024*256;      // 5,505,024
static constexpr int CKT_OFF = WT_END;                   // 6 x 64 x [64 d4][48 p][4 c]
static constexpr int CV_OFF  = CKT_OFF + 6*64*48*256;    // 10,223,616 ; [l][b*48+p][256]
static constexpr int SKT_OFF = CV_OFF  + 6*64*48*256;    // 14,942,208
static constexpr int SV_OFF  = SKT_OFF + 6*64*48*256;    // 19,660,800
static constexpr int WS_END  = SV_OFF  + 6*64*48*256;    // 24,379,392 floats = 97.5 MB
// encoder-time aliases (dead before the regions' real use):
static constexpr int X_OFF    = 0;                       // 786,432 (inside SWQKVT)
static constexpr int MEM_OFF  = X_OFF + 3072*256;        // 786,432..1,572,864 (inside SWQKVT)
static constexpr int QKV_OFF  = SKT_OFF;                 // 2,359,296
static constexpr int AO_OFF   = QKV_OFF + 3072*768;      // 786,432
static constexpr int RES1_OFF = AO_OFF + 3072*256;
static constexpr int X1_OFF   = RES1_OFF + 3072*256;     // ends exactly at SV_OFF
static constexpr int HB_OFF   = SV_OFF;                  // 3,145,728
static constexpr int RES2_OFF = HB_OFF + 3072*1024;      // fits before WS_END
// plain cross-K (pre-transpose temp) lives at SKT_OFF (dead before decode writes SKT)
static constexpr int PCK_OFF  = SKT_OFF;
// ---- decode row-publish buffers (NEW, beyond WS_END; +114,688 floats = 0.46 MB) ----
static constexpr int RB0_OFF  = WS_END;                  // 64 x 256 (q / cross-q)
static constexpr int RB1_OFF  = RB0_OFF + 64*256;        // 64 x 256 (y1 / y2 pre-LN)
static constexpr int RB2_OFF  = RB1_OFF + 64*256;        // 64 x 256 (ffn out pre-LN)
static constexpr int HBR_OFF  = RB2_OFF + 64*256;        // 64 x 1024 (ffn hidden)
static constexpr int WS_END2  = HBR_OFF + 64*1024;       // 24,494,080 floats = 98.0 MB

struct GParams {
  const int   *xc, *xct;
  const float *sos, *emb, *hw, *hb;
  const float *ewqkv, *ebqkv, *ewo, *ebo, *ew1, *eb1, *ew2, *eb2, *elnw, *elnb;
  const float *swqkv, *sbqkv, *swo, *sbo;
  const float *cwqkv, *cbqkv, *cwo, *cbo;
  const float *dw1, *db1, *dw2, *db2, *dlnw, *dlnb, *lnfw, *lnfb;
  float *out;
  float *ws;
};

// ---- device-global barrier state (generation counters survive graph replays) ----
__device__ unsigned g_cntA = 0, g_genA = 0;
__device__ unsigned g_gc[64], g_gg[64];   // per-row-group (4 WG) barriers

static __device__ __forceinline__ void gbar(unsigned* cnt, unsigned* gen, unsigned nb) {
  __syncthreads();
  if (threadIdx.x == 0) {
    __threadfence();
    unsigned g = __hip_atomic_load(gen, __ATOMIC_RELAXED, __HIP_MEMORY_SCOPE_AGENT);
    unsigned prev = __hip_atomic_fetch_add(cnt, 1u, __ATOMIC_ACQ_REL, __HIP_MEMORY_SCOPE_AGENT);
    if (prev == nb - 1u) {
      __hip_atomic_store(cnt, 0u, __ATOMIC_RELAXED, __HIP_MEMORY_SCOPE_AGENT);
      __threadfence();
      __hip_atomic_store(gen, g + 1u, __ATOMIC_RELEASE, __HIP_MEMORY_SCOPE_AGENT);
    } else {
      while (__hip_atomic_load(gen, __ATOMIC_ACQUIRE, __HIP_MEMORY_SCOPE_AGENT) == g)
        __builtin_amdgcn_s_sleep(1);
      __threadfence();
    }
  }
  __syncthreads();
}

// 4-WG group barrier (group = batch row). Same generation pattern as gbar.
static __device__ __forceinline__ void gbar4(int grp) {
  __syncthreads();
  if (threadIdx.x == 0) {
    __threadfence();
    unsigned* cnt = &g_gc[grp];
    unsigned* gen = &g_gg[grp];
    unsigned g = __hip_atomic_load(gen, __ATOMIC_RELAXED, __HIP_MEMORY_SCOPE_AGENT);
    unsigned prev = __hip_atomic_fetch_add(cnt, 1u, __ATOMIC_ACQ_REL, __HIP_MEMORY_SCOPE_AGENT);
    if (prev == 3u) {
      __hip_atomic_store(cnt, 0u, __ATOMIC_RELAXED, __HIP_MEMORY_SCOPE_AGENT);
      __threadfence();
      __hip_atomic_store(gen, g + 1u, __ATOMIC_RELEASE, __HIP_MEMORY_SCOPE_AGENT);
    } else {
      while (__hip_atomic_load(gen, __ATOMIC_ACQUIRE, __HIP_MEMORY_SCOPE_AGENT) == g)
        __builtin_amdgcn_s_sleep(1);
      __threadfence();
    }
  }
  __syncthreads();
}

// ---- threefry2x32 (exact jax rotation/key schedule) ----
static __device__ __forceinline__ void tf2x32(unsigned k0, unsigned k1, unsigned& x0, unsigned& x1) {
  unsigned ks2 = k0 ^ k1 ^ 0x1BD11BDAu;
  x0 += k0; x1 += k1;
#define TF_R(r) { x0 += x1; x1 = (x1 << r) | (x1 >> (32 - r)); x1 ^= x0; }
  TF_R(13) TF_R(15) TF_R(26) TF_R(6)   x0 += k1;  x1 += ks2 + 1u;
  TF_R(17) TF_R(29) TF_R(16) TF_R(24)  x0 += ks2; x1 += k0  + 2u;
  TF_R(13) TF_R(15) TF_R(26) TF_R(6)   x0 += k0;  x1 += k1  + 3u;
  TF_R(17) TF_R(29) TF_R(16) TF_R(24)  x0 += k1;  x1 += ks2 + 4u;
  TF_R(13) TF_R(15) TF_R(26) TF_R(6)   x0 += ks2; x1 += k0  + 5u;
#undef TF_R
}

static __device__ __forceinline__ void step_key(int i, unsigned& k0, unsigned& k1) {
#if JAX_PARTITIONABLE
  unsigned x0 = 0u, x1 = (unsigned)i;
  tf2x32(0u, 42u, x0, x1);
  k0 = x0; k1 = x1;
#else
  unsigned w[2];
  for (int wi = 0; wi < 2; wi++) {
    unsigned o = (unsigned)(2*i + wi), x0, x1;
    if (o < 48u) { x0 = o; x1 = 48u + o; tf2x32(0u, 42u, x0, x1); w[wi] = x0; }
    else         { x0 = o - 48u; x1 = o; tf2x32(0u, 42u, x0, x1); w[wi] = x1; }
  }
  k0 = w[0]; k1 = w[1];
#endif
}

static __device__ __forceinline__ unsigned gumbel_bits(unsigned k0, unsigned k1, int b, int v) {
#if JAX_PARTITIONABLE
  unsigned x0 = 0u, x1 = (unsigned)(b*1024 + v);
  tf2x32(k0, k1, x0, x1);
  return x0 ^ x1;
#else
  unsigned jj = (unsigned)((b & 31)*1024 + v);
  unsigned x0 = jj, x1 = 32768u + jj;
  tf2x32(k0, k1, x0, x1);
  return (b < 32) ? x0 : x1;
#endif
}

// ---- positional encoding element ----
static __device__ __forceinline__ float pe_val(int p, int c) {
  const float KC = (float)(-9.210340371976184 / 256.0);
  int j = c >> 1;
  float dv = expf((float)(2*j) * KC);
  float a = (float)p * dv;
  return (c & 1) ? cosf(a) : sinf(a);
}

// ---- per-wave LayerNorm of a 256-float LDS row (call with one full wave) ----
static __device__ __forceinline__ void wave_ln_row(float* row, const float* lw, const float* lb) {
  const int lane = threadIdx.x & 63;
  float x0 = row[lane], x1 = row[lane+64], x2 = row[lane+128], x3 = row[lane+192];
  float s = (x0 + x1) + (x2 + x3);
#pragma unroll
  for (int m = 1; m < 64; m <<= 1) s += __shfl_xor(s, m);
  float mean = s * 0.00390625f;
  float d0 = x0-mean, d1 = x1-mean, d2 = x2-mean, d3 = x3-mean;
  float q = (d0*d0 + d1*d1) + (d2*d2 + d3*d3);
#pragma unroll
  for (int m = 1; m < 64; m <<= 1) q += __shfl_xor(q, m);
  float rs = 1.0f / sqrtf(q * 0.00390625f + 1e-5f);
  row[lane]     = d0*rs*lw[lane]     + lb[lane];
  row[lane+64]  = d1*rs*lw[lane+64]  + lb[lane+64];
  row[lane+128] = d2*rs*lw[lane+128] + lb[lane+128];
  row[lane+192] = d3*rs*lw[lane+192] + lb[lane+192];
}

// ---- column-sliced matvec partials: wt is [K][C] (k-major), x in LDS ----
// Computes output cols [c0, c0+CS). Thread (kc,o): scalar column o, k-chunk kc.
// K-chunking (KS) and per-output sequential-k FMA order match the previous
// full-width matvec_t bitwise, so a 4-way column split is numerically exact.
template<int C, int CS, int KS, int K>
static __device__ void matvec_sp(const float* __restrict__ wt, int c0,
                                 const float* __restrict__ x, float* __restrict__ part) {
  const int t = threadIdx.x;
  constexpr int KC = K/KS;
  if (t < CS*KS) {
    const int kc = t / CS, o = t - kc*CS;
    const int k0 = kc*KC;
    float acc = 0.0f;
    const float* wp = wt + k0*C + c0 + o;
#pragma unroll 32
    for (int k = 0; k < KC; k++)
      acc += x[k0 + k] * wp[k*C];
    part[kc*CS + o] = acc;
  }
  __syncthreads();
}

// ---- encoder tiled GEMM stage (unchanged) ----
static __device__ void gemm_stage(const float* __restrict__ A, const float* __restrict__ W,
                                  const float* __restrict__ bias, const float* __restrict__ res,
                                  float* __restrict__ out, int R, int C, int K, int relu,
                                  float* sA) {
  const int t = threadIdx.x;
  const bool act = (t < 256);
  const int lane = t & 63, wv = (t >> 6) & 3;
  const int ntc = C >> 6;
  const int ntiles = (R >> 5) * ntc;
  for (int tile = blockIdx.x; tile < ntiles; tile += gridDim.x) {
    const int tr = tile / ntc, tc = tile - tr*ntc;
    const int r0 = tr << 5;
    const int c  = (tc << 6) + lane;
    float acc[8] = {0,0,0,0,0,0,0,0};
    for (int kc = 0; kc < K; kc += 256) {
      __syncthreads();
      if (act) {
#pragma unroll
        for (int u = 0; u < 8; u++) {
          int idx = u*256 + t;
          int rr = idx >> 6, cc = idx & 63;
          ((float4*)sA)[idx] = *(const float4*)(A + (r0+rr)*K + kc + cc*4);
        }
      }
      __syncthreads();
      if (act) {
        const float* wr = W + c*K + kc;
        for (int k = 0; k < 256; k += 4) {
          float4 w4 = *(const float4*)(wr + k);
#pragma unroll
          for (int r = 0; r < 8; r++) {
            float4 a4 = *(const float4*)(sA + (wv*8 + r)*256 + k);
            acc[r] += a4.x*w4.x; acc[r] += a4.y*w4.y; acc[r] += a4.z*w4.z; acc[r] += a4.w*w4.w;
          }
        }
      }
    }
    if (act) {
      float bb = bias ? bias[c] : 0.0f;
#pragma unroll
      for (int r = 0; r < 8; r++) {
        int row = r0 + wv*8 + r;
        float v = acc[r] + bb;
        if (relu) v = fmaxf(v, 0.0f);
        if (res)  v += res[row*C + c];
        out[row*C + c] = v;
      }
    }
  }
}

// ---- encoder LN stage ----
static __device__ void ln_stage(const float* in, const float* lw, const float* lb,
                                float* out, int R) {
  const int lane = threadIdx.x & 63;
  int gw = blockIdx.x*8 + (threadIdx.x >> 6);
  for (int row = gw; row < R; row += gridDim.x*8) {
    const float* ir = in + row*256;
    float x0 = ir[lane], x1 = ir[lane+64], x2 = ir[lane+128], x3 = ir[lane+192];
    float s = (x0 + x1) + (x2 + x3);
#pragma unroll
    for (int m = 1; m < 64; m <<= 1) s += __shfl_xor(s, m);
    float mean = s * 0.00390625f;
    float d0 = x0-mean, d1 = x1-mean, d2 = x2-mean, d3 = x3-mean;
    float q = (d0*d0 + d1*d1) + (d2*d2 + d3*d3);
#pragma unroll
    for (int m = 1; m < 64; m <<= 1) q += __shfl_xor(q, m);
    float rs = 1.0f / sqrtf(q * 0.00390625f + 1e-5f);
    float* orow = out + row*256;
    orow[lane]     = d0*rs*lw[lane]     + lb[lane];
    orow[lane+64]  = d1*rs*lw[lane+64]  + lb[lane+64];
    orow[lane+128] = d2*rs*lw[lane+128] + lb[lane+128];
    orow[lane+192] = d3*rs*lw[lane+192] + lb[lane+192];
  }
}

// ---- encoder attention core (unchanged; K rows in [p][d] layout) ----
static __device__ void attn_core(const float* qd, const float* kb, const float* vb,
                                 int krstride, int kstride, int nk,
                                 float* sc, float* red, float* ao) {
  const int t = threadIdx.x;
  const int r = t >> 5, p0 = t & 31;
  const bool act = (t < 256);
  if (act) {
#pragma unroll
    for (int pass = 0; pass < 2; pass++) {
      int p = pass*32 + p0;
      if (p < nk) {
        const float4* k4 = (const float4*)(kb + r*krstride + p*kstride);
        const float4* q4 = (const float4*)(qd + r*32);
        float a = 0.0f;
#pragma unroll
        for (int d4 = 0; d4 < 8; d4++) {
          float4 kv = k4[d4], qv = q4[d4];
          a += qv.x*kv.x; a += qv.y*kv.y; a += qv.z*kv.z; a += qv.w*kv.w;
        }
        sc[r*48 + p] = a * 0.17677669529663687f;
      }
    }
  }
  __syncthreads();
  if (t < 8) {
    float m = sc[t*48];
    for (int p = 1; p < nk; p++) m = fmaxf(m, sc[t*48 + p]);
    red[t] = m;
  }
  __syncthreads();
  if (act) {
#pragma unroll
    for (int pass = 0; pass < 2; pass++) {
      int p = pass*32 + p0;
      if (p < nk) sc[r*48 + p] = expf(sc[r*48 + p] - red[r]);
    }
  }
  __syncthreads();
  if (t < 8) {
    float s = 0.0f;
    for (int p = 0; p < nk; p++) s += sc[t*48 + p];
    red[8 + t] = s;
  }
  __syncthreads();
  if (act) {
#pragma unroll
    for (int pass = 0; pass < 2; pass++) {
      int p = pass*32 + p0;
      if (p < nk) sc[r*48 + p] = sc[r*48 + p] / red[8 + r];
    }
  }
  __syncthreads();
  if (act) {
    const int d2 = t & 31;
    const float* vr = vb + r*krstride + d2;
    float a = 0.0f;
    for (int p = 0; p < nk; p++) a += sc[r*48 + p] * vr[p*kstride];
    ao[r*32 + d2] = a;
  }
  __syncthreads();
}

static __device__ void enc_attn_stage(const float* QKV, float* AO, float* sm) {
  const int t = threadIdx.x;
  const bool act = (t < 256);
  float* qd  = sm;
  float* sc  = sm + 256;
  float* ao  = sm + 640;
  float* red = sm + 896;
  for (int pi = blockIdx.x; pi < 512; pi += gridDim.x) {
    int b = pi >> 3, h = pi & 7;
    const float* Qb = QKV + b*48*768 + h*32;
    const float* Kb = QKV + b*48*768 + 256 + h*32;
    const float* Vb = QKV + b*48*768 + 512 + h*32;
    for (int qg = 0; qg < 6; qg++) {
      if (act) { int r = t >> 5, d2 = t & 31; qd[r*32 + d2] = Qb[(qg*8 + r)*768 + d2]; }
      __syncthreads();
      attn_core(qd, Kb, Vb, 0, 768, 48, sc, red, ao);
      if (act) { int r = t >> 5, d2 = t & 31; AO[(b*48 + qg*8 + r)*256 + h*32 + d2] = ao[r*32 + d2]; }
      __syncthreads();
    }
  }
}

// ---- decode attention: K transposed [d4][p][4] (coalesced over p); V in [p][d] ----
static __device__ void attn_dec(const float* qd, const float* kt, const float* v,
                                int nk, float* sc, float* red, float* ao) {
  const int t = threadIdx.x;
  const int r = t >> 5, p0 = t & 31;
  const bool act = (t < 256);
  if (act) {
    const float4* q4 = (const float4*)(qd + r*32);
#pragma unroll
    for (int pass = 0; pass < 2; pass++) {
      int p = pass*32 + p0;
      if (p < nk) {
        const float* kb = kt + r*1536 + p*4;   // r = head; 8 d4-blocks of 192 floats
        float a = 0.0f;
#pragma unroll
        for (int j = 0; j < 8; j++) {
          float4 kv = *(const float4*)(kb + j*192);
          float4 qv = q4[j];
          a += qv.x*kv.x; a += qv.y*kv.y; a += qv.z*kv.z; a += qv.w*kv.w;
        }
        sc[r*48 + p] = a * 0.17677669529663687f;
      }
    }
  }
  __syncthreads();
  if (t < 8) {
    float m = sc[t*48];
    for (int p = 1; p < nk; p++) m = fmaxf(m, sc[t*48 + p]);
    red[t] = m;
  }
  __syncthreads();
  if (act) {
#pragma unroll
    for (int pass = 0; pass < 2; pass++) {
      int p = pass*32 + p0;
      if (p < nk) sc[r*48 + p] = expf(sc[r*48 + p] - red[r]);
    }
  }
  __syncthreads();
  if (t < 8) {
    float s = 0.0f;
    for (int p = 0; p < nk; p++) s += sc[t*48 + p];
    red[8 + t] = s;
  }
  __syncthreads();
  if (act) {
#pragma unroll
    for (int pass = 0; pass < 2; pass++) {
      int p = pass*32 + p0;
      if (p < nk) sc[r*48 + p] = sc[r*48 + p] / red[8 + r];
    }
  }
  __syncthreads();
  if (act) {
    const int d2 = t & 31;
    const float* vr = v + r*32 + d2;
    float a = 0.0f;
    for (int p = 0; p < nk; p++) a += sc[r*48 + p] * vr[p*256];
    ao[r*32 + d2] = a;
  }
  __syncthreads();
}

// ================= the single persistent kernel =================
__global__ void __launch_bounds__(512)
genrev4_kernel(GParams P) {
  __shared__ float sm[8448];
  float* ws = P.ws;
  const int wg = blockIdx.x;
  const int t  = threadIdx.x;

  // ---- E0: encoder embeddings + pe ----
  if (t < 256) {
    for (int rr = 0; rr < 12; rr++) {
      int row = wg*12 + rr;
      int b = row / 48, s = row % 48;
      int tok = (s < 32) ? P.xc[b*32 + s] : P.xct[b*16 + (s - 32)];
      ws[X_OFF + row*256 + t] = P.emb[(s*1024 + tok)*256 + t] + pe_val(s, t);
    }
  }
  gbar(&g_cntA, &g_genA, 256);

  // ---- encoder: 6 post-norm layers ----
  float* Xp = ws + X_OFF;
  for (int l = 0; l < 6; l++) {
    gemm_stage(Xp, P.ewqkv + l*768*256, P.ebqkv + l*768, nullptr, ws + QKV_OFF, 3072, 768, 256, 0, sm);
    gbar(&g_cntA, &g_genA, 256);
    enc_attn_stage(ws + QKV_OFF, ws + AO_OFF, sm);
    gbar(&g_cntA, &g_genA, 256);
    gemm_stage(ws + AO_OFF, P.ewo + l*256*256, P.ebo + l*256, Xp, ws + RES1_OFF, 3072, 256, 256, 0, sm);
    gbar(&g_cntA, &g_genA, 256);
    ln_stage(ws + RES1_OFF, P.elnw + (l*2 + 0)*256, P.elnb + (l*2 + 0)*256, ws + X1_OFF, 3072);
    gbar(&g_cntA, &g_genA, 256);
    gemm_stage(ws + X1_OFF, P.ew1 + l*1024*256, P.eb1 + l*1024, nullptr, ws + HB_OFF, 3072, 1024, 256, 1, sm);
    gbar(&g_cntA, &g_genA, 256);
    gemm_stage(ws + HB_OFF, P.ew2 + l*256*1024, P.eb2 + l*256, ws + X1_OFF, ws + RES2_OFF, 3072, 256, 1024, 0, sm);
    gbar(&g_cntA, &g_genA, 256);
    ln_stage(ws + RES2_OFF, P.elnw + (l*2 + 1)*256, P.elnb + (l*2 + 1)*256, Xp, 3072);
    gbar(&g_cntA, &g_genA, 256);
  }
  ln_stage(Xp, P.lnfw, P.lnfb, ws + MEM_OFF, 3072);
  gbar(&g_cntA, &g_genA, 256);
  // cross K (plain, temp at PCK) and cross V (final layout) for all 6 layers
  for (int l = 0; l < 6; l++) {
    gemm_stage(ws + MEM_OFF, P.cwqkv + (l*768 + 256)*256, P.cbqkv + l*768 + 256, nullptr,
               ws + PCK_OFF + l*786432, 3072, 256, 256, 0, sm);
    gemm_stage(ws + MEM_OFF, P.cwqkv + (l*768 + 512)*256, P.cbqkv + l*768 + 512, nullptr,
               ws + CV_OFF + l*786432, 3072, 256, 256, 0, sm);
  }
  gbar(&g_cntA, &g_genA, 256);

  // ---- transpose phase: decode weights -> [k][o]; plain cross-K -> [d4][p][4] ----
  {
    const int gt = wg*512 + t;
    const int GT = 256*512;
    for (int idx = gt; idx < 6*256*768; idx += GT) {
      int l = idx / 196608, r = idx - l*196608;
      int k = r / 768, o = r - k*768;
      ws[SWQKVT + idx] = P.swqkv[(l*768 + o)*256 + k];
    }
    for (int idx = gt; idx < 6*65536; idx += GT) {
      int l = idx >> 16, r = idx & 65535, k = r >> 8, o = r & 255;
      ws[SWOT + idx] = P.swo[(l*256 + o)*256 + k];
    }
    for (int idx = gt; idx < 6*65536; idx += GT) {
      int l = idx >> 16, r = idx & 65535, k = r >> 8, o = r & 255;
      ws[CWQT + idx] = P.cwqkv[(l*768 + o)*256 + k];
    }
    for (int idx = gt; idx < 6*65536; idx += GT) {
      int l = idx >> 16, r = idx & 65535, k = r >> 8, o = r & 255;
      ws[CWOT + idx] = P.cwo[(l*256 + o)*256 + k];
    }
    for (int idx = gt; idx < 6*262144; idx += GT) {
      int l = idx >> 18, r = idx & 262143, k = r >> 10, o = r & 1023;
      ws[DW1T + idx] = P.dw1[(l*1024 + o)*256 + k];
    }
    for (int idx = gt; idx < 6*262144; idx += GT) {
      int l = idx >> 18, r = idx & 262143, k = r >> 8, o = r & 255;
      ws[DW2T + idx] = P.dw2[(l*256 + o)*1024 + k];
    }
    // CKT[l][b][d4][p][c] from plain CK[l][b*48+p][d]
    for (int idx = gt; idx < 6*64*48*256; idx += GT) {
      int l = idx / 786432, r = idx - l*786432;
      int b = r / 12288, q = r - b*12288;
      int d4 = q / 192, s2 = q - d4*192;
      int p = s2 >> 2, c = s2 & 3;
      ws[CKT_OFF + idx] = ws[PCK_OFF + l*786432 + (b*48 + p)*256 + d4*4 + c];
    }
  }
  gbar(&g_cntA, &g_genA, 256);

  // ================= decode: 4 WGs per batch row (tensor-parallel col split) ===========
  // b = wg>>2, g = wg&3: same-g cohorts land on XCDs {g, g+4} -> weight slices are
  // L2-resident for the 32 same-g WGs on each XCD. Matvec outputs are column-sliced
  // (bitwise-identical k-chunk order); row-local ops (attn, LN, sampling) run
  // redundantly in all 4 group members. 6 gbar4/layer + 1/head = 37 per step.
  const int b = wg >> 2;
  const int g = wg & 3;

  float* cur  = sm;           // 256
  float* qv   = sm + 256;     // 256
  float* av   = sm + 512;     // 256
  float* y1   = sm + 768;     // 256
  float* y2   = sm + 1024;    // 256
  float* hbf  = sm + 1280;    // 1024
  float* sc   = sm + 2304;    // 384
  float* red  = sm + 2688;    // 32
  float* y0   = sm + 2720;    // 256
  float* bvv  = sm + 2976;    // 256
  int*   bii  = (int*)(sm + 3232); // 256
  float* part = sm + 3488;    // 2048

  if (t < 256) y0[t] = P.sos[t] + pe_val(0, t);
  __syncthreads();

  for (int i = 0; i < 48; i++) {
    if (t < 256) cur[t] = y0[t];
    __syncthreads();
    for (int l = 0; l < 6; l++) {
      const int skt = SKT_OFF + l*786432 + b*12288;
      const int sv  = SV_OFF  + l*786432 + b*12288;
      const int ckt = CKT_OFF + l*786432 + b*12288;
      const int cv  = CV_OFF  + l*786432 + b*12288;
      // --- P1: self QKV, cols [g*192, g*192+192) (KS=2 as before) ---
      matvec_sp<768,192,2,256>(ws + SWQKVT + l*196608, g*192, cur, part);
      if (t < 192) {
        int oa = g*192 + t;
        float s = part[t] + part[192 + t] + P.sbqkv[l*768 + oa];
        if (oa < 256)      ws[RB0_OFF + b*256 + oa] = s;
        else if (oa < 512) { int d = oa - 256; ws[skt + (d>>2)*192 + i*4 + (d&3)] = s; }
        else               ws[sv + i*256 + (oa - 512)] = s;
      }
      gbar4(b);
      // --- P2: self attention (redundant in all 4 WGs) ---
      if (t < 256) qv[t] = ws[RB0_OFF + b*256 + t];
      __syncthreads();
      attn_dec(qv, ws + skt, ws + sv, i + 1, sc, red, av);
      // --- P3: self out-proj cols [g*64, g*64+64) + residual ---
      matvec_sp<256,64,8,256>(ws + SWOT + l*65536, g*64, av, part);
      if (t < 64) {
        int oa = g*64 + t;
        float s = part[t];
#pragma unroll
        for (int kc = 1; kc < 8; kc++) s += part[kc*64 + t];
        ws[RB1_OFF + b*256 + oa] = cur[oa] + (s + P.sbo[l*256 + oa]);
      }
      gbar4(b);
      // --- P4: LN1 (redundant) ---
      if (t < 256) y1[t] = ws[RB1_OFF + b*256 + t];
      __syncthreads();
      if (t < 64) wave_ln_row(y1, P.dlnw + (l*3 + 0)*256, P.dlnb + (l*3 + 0)*256);
      __syncthreads();
      // --- P5: cross-q cols ---
      matvec_sp<256,64,8,256>(ws + CWQT + l*65536, g*64, y1, part);
      if (t < 64) {
        int oa = g*64 + t;
        float s = part[t];
#pragma unroll
        for (int kc = 1; kc < 8; kc++) s += part[kc*64 + t];
        ws[RB0_OFF + b*256 + oa] = s + P.cbqkv[l*768 + oa];
      }
      gbar4(b);
      // --- P6: cross attention (redundant) ---
      if (t < 256) qv[t] = ws[RB0_OFF + b*256 + t];
      __syncthreads();
      attn_dec(qv, ws + ckt, ws + cv, 48, sc, red, av);
      // --- P7: cross out-proj cols + residual ---
      matvec_sp<256,64,8,256>(ws + CWOT + l*65536, g*64, av, part);
      if (t < 64) {
        int oa = g*64 + t;
        float s = part[t];
#pragma unroll
        for (int kc = 1; kc < 8; kc++) s += part[kc*64 + t];
        ws[RB1_OFF + b*256 + oa] = y1[oa] + (s + P.cbo[l*256 + oa]);
      }
      gbar4(b);
      // --- P8: LN2 ---
      if (t < 256) y2[t] = ws[RB1_OFF + b*256 + t];
      __syncthreads();
      if (t < 64) wave_ln_row(y2, P.dlnw + (l*3 + 1)*256, P.dlnb + (l*3 + 1)*256);
      __syncthreads();
      // --- P9: FFN1 cols [g*256, g*256+256) + relu (KS=2 as before) ---
      matvec_sp<1024,256,2,256>(ws + DW1T + l*262144, g*256, y2, part);
      if (t < 256) {
        int oa = g*256 + t;
        ws[HBR_OFF + b*1024 + oa] = fmaxf(part[t] + part[256 + t] + P.db1[l*1024 + oa], 0.0f);
      }
      gbar4(b);
      // --- P10: FFN2 cols + residual (KS=8, K=1024 as before) ---
      for (int o = t; o < 1024; o += 512) hbf[o] = ws[HBR_OFF + b*1024 + o];
      __syncthreads();
      matvec_sp<256,64,8,1024>(ws + DW2T + l*262144, g*64, hbf, part);
      if (t < 64) {
        int oa = g*64 + t;
        float s = part[t];
#pragma unroll
        for (int kc = 1; kc < 8; kc++) s += part[kc*64 + t];
        ws[RB2_OFF + b*256 + oa] = y2[oa] + (s + P.db2[l*256 + oa]);
      }
      gbar4(b);
      // --- P11: LN3 ---
      if (t < 256) cur[t] = ws[RB2_OFF + b*256 + t];
      __syncthreads();
      if (t < 64) wave_ln_row(cur, P.dlnw + (l*3 + 2)*256, P.dlnb + (l*3 + 2)*256);
      __syncthreads();
    }
    // --- final LN (lnf[1]) ---
    if (t < 64) wave_ln_row(cur, P.lnfw + 256, P.lnfb + 256);
    __syncthreads();
    // --- head: cols [g*256, g*256+256), wave-cooperative rows, write straight to out ---
    {
      const int wv = t >> 6, lane = t & 63;
      const float4 x4 = *(const float4*)(cur + lane*4);
      float* outrow = P.out + 3072 + (size_t)i*65536 + b*1024;
      for (int base = 0; base < 256; base += 16) {
        int o = g*256 + base + wv, o2 = o + 8;
        float4 wa = *(const float4*)(P.hw + (size_t)(i*1024 + o)*256 + lane*4);
        float4 wb = *(const float4*)(P.hw + (size_t)(i*1024 + o2)*256 + lane*4);
        float sa = wa.x*x4.x; sa += wa.y*x4.y; sa += wa.z*x4.z; sa += wa.w*x4.w;
        float sb = wb.x*x4.x; sb += wb.y*x4.y; sb += wb.z*x4.z; sb += wb.w*x4.w;
#pragma unroll
        for (int m = 1; m < 64; m <<= 1) { sa += __shfl_xor(sa, m); sb += __shfl_xor(sb, m); }
        if (lane == 0) {
          outrow[o]  = sa + P.hb[i*1024 + o];
          outrow[o2] = sb + P.hb[i*1024 + o2];
        }
      }
    }
    gbar4(b);
    {
      const float* outrow = P.out + 3072 + (size_t)i*65536 + b*1024;
      for (int o = t; o < 1024; o += 512) hbf[o] = outrow[o];
    }
    __syncthreads();
    // --- gumbel-argmax sampling (redundant; bitwise identical in all 4 WGs) ---
    unsigned k0, k1;
    step_key(i, k0, k1);
    if (t < 256) {
      float bestv = -INFINITY; int besti = 0;
#pragma unroll
      for (int e = 0; e < 4; e++) {
        int v = t*4 + e;
        unsigned bits = gumbel_bits(k0, k1, b, v);
        float f = __uint_as_float((bits >> 9) | 0x3f800000u);
        float u = fmaxf(f - 1.0f, 1.17549435e-38f);
        float gg = -logf(-logf(u));
        float z = gg + hbf[v] / 0.1f;
        if (z > bestv) { bestv = z; besti = v; }
      }
      bvv[t] = bestv; bii[t] = besti;
    }
    __syncthreads();
    for (int s = 128; s > 0; s >>= 1) {
      if (t < s) {
        float ov = bvv[t+s]; int oi = bii[t+s];
        if (ov > bvv[t] || (ov == bvv[t] && oi < bii[t])) { bvv[t] = ov; bii[t] = oi; }
      }
      __syncthreads();
    }
    const int ch = bii[0];
    if (t == 0 && g == 0) {
      if (i < 32) P.out[b*32 + i] = (float)ch;
      else        P.out[2048 + b*16 + (i - 32)] = (float)ch;
    }
    if (t < 256) y0[t] = P.emb[(i*1024 + ch)*256 + t] + pe_val(i + 1, t);
    __syncthreads();
  }
}

extern "C" void kernel_launch(void* const* d_in, const int* in_sizes, int n_in,
                              void* d_out, int out_size, void* d_ws, size_t ws_size,
                              hipStream_t stream) {
  (void)in_sizes; (void)n_in; (void)out_size; (void)ws_size;
  GParams p;
  p.xc    = (const int*)  d_in[0];
  p.xct   = (const int*)  d_in[1];
  p.sos   = (const float*)d_in[2];
  p.emb   = (const float*)d_in[3];
  p.hw    = (const float*)d_in[4];
  p.hb    = (const float*)d_in[5];
  p.ewqkv = (const float*)d_in[6];
  p.ebqkv = (const float*)d_in[7];
  p.ewo   = (const float*)d_in[8];
  p.ebo   = (const float*)d_in[9];
  p.ew1   = (const float*)d_in[10];
  p.eb1   = (const float*)d_in[11];
  p.ew2   = (const float*)d_in[12];
  p.eb2   = (const float*)d_in[13];
  p.elnw  = (const float*)d_in[14];
  p.elnb  = (const float*)d_in[15];
  p.swqkv = (const float*)d_in[16];
  p.sbqkv = (const float*)d_in[17];
  p.swo   = (const float*)d_in[18];
  p.sbo   = (const float*)d_in[19];
  p.cwqkv = (const float*)d_in[20];
  p.cbqkv = (const float*)d_in[21];
  p.cwo   = (const float*)d_in[22];
  p.cbo   = (const float*)d_in[23];
  p.dw1   = (const float*)d_in[24];
  p.db1   = (const float*)d_in[25];
  p.dw2   = (const float*)d_in[26];
  p.db2   = (const float*)d_in[27];
  p.dlnw  = (const float*)d_in[28];
  p.dlnb  = (const float*)d_in[29];
  p.lnfw  = (const float*)d_in[30];
  p.lnfb  = (const float*)d_in[31];
  p.out   = (float*)d_out;
  p.ws    = (float*)d_ws;
  hipLaunchKernelGGL(genrev4_kernel, dim3(256), dim3(512), 0, stream, p);
}

// Round 2
// 23417.438 us; speedup vs baseline: 3.4830x; 3.4830x over previous
//
#include <hip/hip_runtime.h>
#include <math.h>

// ===== jax threefry mode: 1 = partitionable (jax >= 0.4.36 default) =====
#define JAX_PARTITIONABLE 1

// ---- model dims: NL=6 D=256 FF=1024 V=1024 S=48 BS=64 H=8 DH=32 ----

// ---- workspace layout (float offsets) ----
// Transposed decode weights (built after encoder; region doubles as X/MEM during encoder)
static constexpr int SWQKVT  = 0;                        // 6 x [256 k][768 o]
static constexpr int SWOT    = SWQKVT + 6*256*768;       // 1,179,648 ; 6 x [256][256]
static constexpr int CWQT    = SWOT   + 6*256*256;       // 1,572,864
static constexpr int CWOT    = CWQT   + 6*256*256;       // 1,966,080
static constexpr int DW1T    = CWOT   + 6*256*256;       // 2,359,296 ; 6 x [256][1024]
static constexpr int DW2T    = DW1T   + 6*256*1024;      // 3,932,160 ; 6 x [1024][256]
static constexpr int WT_END  = DW2T   + 6*1024*256;      // 5,505,024
static constexpr int CKT_OFF = WT_END;                   // 6 x 64 x [64 d4][48 p][4 c]
static constexpr int CV_OFF  = CKT_OFF + 6*64*48*256;    // 10,223,616 ; [l][b*48+p][256]
static constexpr int SKT_OFF = CV_OFF  + 6*64*48*256;    // 14,942,208
static constexpr int SV_OFF  = SKT_OFF + 6*64*48*256;    // 19,660,800
static constexpr int WS_END  = SV_OFF  + 6*64*48*256;    // 24,379,392 floats = 97.5 MB
// encoder-time aliases (dead before the regions' real use):
static constexpr int X_OFF    = 0;                       // 786,432 (inside SWQKVT)
static constexpr int MEM_OFF  = X_OFF + 3072*256;        // 786,432..1,572,864 (inside SWQKVT)
static constexpr int QKV_OFF  = SKT_OFF;                 // 2,359,296
static constexpr int AO_OFF   = QKV_OFF + 3072*768;      // 786,432
static constexpr int RES1_OFF = AO_OFF + 3072*256;
static constexpr int X1_OFF   = RES1_OFF + 3072*256;     // ends exactly at SV_OFF
static constexpr int HB_OFF   = SV_OFF;                  // 3,145,728
static constexpr int RES2_OFF = HB_OFF + 3072*1024;      // fits before WS_END
// plain cross-K (pre-transpose temp) lives at SKT_OFF (dead before decode writes SKT)
static constexpr int PCK_OFF  = SKT_OFF;

struct GParams {
  const int   *xc, *xct;
  const float *sos, *emb, *hw, *hb;
  const float *ewqkv, *ebqkv, *ewo, *ebo, *ew1, *eb1, *ew2, *eb2, *elnw, *elnb;
  const float *swqkv, *sbqkv, *swo, *sbo;
  const float *cwqkv, *cbqkv, *cwo, *cbo;
  const float *dw1, *db1, *dw2, *db2, *dlnw, *dlnb, *lnfw, *lnfb;
  float *out;
  float *ws;
};

// ---- device-global barrier state (generation counters survive graph replays) ----
__device__ unsigned g_cntA = 0, g_genA = 0;

static __device__ __forceinline__ void gbar(unsigned* cnt, unsigned* gen, unsigned nb) {
  __syncthreads();
  if (threadIdx.x == 0) {
    __threadfence();
    unsigned g = __hip_atomic_load(gen, __ATOMIC_RELAXED, __HIP_MEMORY_SCOPE_AGENT);
    unsigned prev = __hip_atomic_fetch_add(cnt, 1u, __ATOMIC_ACQ_REL, __HIP_MEMORY_SCOPE_AGENT);
    if (prev == nb - 1u) {
      __hip_atomic_store(cnt, 0u, __ATOMIC_RELAXED, __HIP_MEMORY_SCOPE_AGENT);
      __threadfence();
      __hip_atomic_store(gen, g + 1u, __ATOMIC_RELEASE, __HIP_MEMORY_SCOPE_AGENT);
    } else {
      while (__hip_atomic_load(gen, __ATOMIC_ACQUIRE, __HIP_MEMORY_SCOPE_AGENT) == g)
        __builtin_amdgcn_s_sleep(1);
      __threadfence();
    }
  }
  __syncthreads();
}

// ---- threefry2x32 (exact jax rotation/key schedule) ----
static __device__ __forceinline__ void tf2x32(unsigned k0, unsigned k1, unsigned& x0, unsigned& x1) {
  unsigned ks2 = k0 ^ k1 ^ 0x1BD11BDAu;
  x0 += k0; x1 += k1;
#define TF_R(r) { x0 += x1; x1 = (x1 << r) | (x1 >> (32 - r)); x1 ^= x0; }
  TF_R(13) TF_R(15) TF_R(26) TF_R(6)   x0 += k1;  x1 += ks2 + 1u;
  TF_R(17) TF_R(29) TF_R(16) TF_R(24)  x0 += ks2; x1 += k0  + 2u;
  TF_R(13) TF_R(15) TF_R(26) TF_R(6)   x0 += k0;  x1 += k1  + 3u;
  TF_R(17) TF_R(29) TF_R(16) TF_R(24)  x0 += k1;  x1 += ks2 + 4u;
  TF_R(13) TF_R(15) TF_R(26) TF_R(6)   x0 += ks2; x1 += k0  + 5u;
#undef TF_R
}

static __device__ __forceinline__ void step_key(int i, unsigned& k0, unsigned& k1) {
#if JAX_PARTITIONABLE
  unsigned x0 = 0u, x1 = (unsigned)i;
  tf2x32(0u, 42u, x0, x1);
  k0 = x0; k1 = x1;
#else
  unsigned w[2];
  for (int wi = 0; wi < 2; wi++) {
    unsigned o = (unsigned)(2*i + wi), x0, x1;
    if (o < 48u) { x0 = o; x1 = 48u + o; tf2x32(0u, 42u, x0, x1); w[wi] = x0; }
    else         { x0 = o - 48u; x1 = o; tf2x32(0u, 42u, x0, x1); w[wi] = x1; }
  }
  k0 = w[0]; k1 = w[1];
#endif
}

static __device__ __forceinline__ unsigned gumbel_bits(unsigned k0, unsigned k1, int b, int v) {
#if JAX_PARTITIONABLE
  unsigned x0 = 0u, x1 = (unsigned)(b*1024 + v);
  tf2x32(k0, k1, x0, x1);
  return x0 ^ x1;
#else
  unsigned jj = (unsigned)((b & 31)*1024 + v);
  unsigned x0 = jj, x1 = 32768u + jj;
  tf2x32(k0, k1, x0, x1);
  return (b < 32) ? x0 : x1;
#endif
}

// ---- positional encoding element ----
static __device__ __forceinline__ float pe_val(int p, int c) {
  const float KC = (float)(-9.210340371976184 / 256.0);
  int j = c >> 1;
  float dv = expf((float)(2*j) * KC);
  float a = (float)p * dv;
  return (c & 1) ? cosf(a) : sinf(a);
}

// ---- per-wave LayerNorm of a 256-float LDS row (call with one full wave) ----
static __device__ __forceinline__ void wave_ln_row(float* row, const float* lw, const float* lb) {
  const int lane = threadIdx.x & 63;
  float x0 = row[lane], x1 = row[lane+64], x2 = row[lane+128], x3 = row[lane+192];
  float s = (x0 + x1) + (x2 + x3);
#pragma unroll
  for (int m = 1; m < 64; m <<= 1) s += __shfl_xor(s, m);
  float mean = s * 0.00390625f;
  float d0 = x0-mean, d1 = x1-mean, d2 = x2-mean, d3 = x3-mean;
  float q = (d0*d0 + d1*d1) + (d2*d2 + d3*d3);
#pragma unroll
  for (int m = 1; m < 64; m <<= 1) q += __shfl_xor(q, m);
  float rs = 1.0f / sqrtf(q * 0.00390625f + 1e-5f);
  row[lane]     = d0*rs*lw[lane]     + lb[lane];
  row[lane+64]  = d1*rs*lw[lane+64]  + lb[lane+64];
  row[lane+128] = d2*rs*lw[lane+128] + lb[lane+128];
  row[lane+192] = d3*rs*lw[lane+192] + lb[lane+192];
}

// ---- transposed coalesced matvec partials: wt is [K][C] (k-major), x in LDS ----
// thread t: kc = t/(C/4) k-chunk, o4 = t%(C/4); acc float4 over its chunk, store to part[kc*C + o].
// Deep-pipelined: 16 float4 weight rows batch-loaded (independent) then consumed in
// strictly ascending k order -> FMA order per output is bitwise identical to the
// previous unroll-4 version; only load scheduling (MLP) changes.
template<int C, int KS, int K>
static __device__ void matvec_t(const float* __restrict__ wt, const float* __restrict__ x,
                                float* __restrict__ part) {
  const int t = threadIdx.x;
  constexpr int O4 = C/4;
  constexpr int KC = K/KS;
  if (t < O4*KS) {
    const int kc = t / O4, o4 = t - kc*O4;
    const int k0 = kc*KC;
    float4 acc = {0.f,0.f,0.f,0.f};
    const float* wp = wt + k0*C + o4*4;
    for (int kb = 0; kb < KC; kb += 16) {
      float4 w[16];
#pragma unroll
      for (int j = 0; j < 16; j++) w[j] = *(const float4*)(wp + (kb + j)*C);
#pragma unroll
      for (int j4 = 0; j4 < 4; j4++) {
        float4 xv = *(const float4*)(x + k0 + kb + j4*4);
        float4 a0 = w[j4*4+0], a1 = w[j4*4+1], a2 = w[j4*4+2], a3 = w[j4*4+3];
        acc.x += xv.x*a0.x; acc.y += xv.x*a0.y; acc.z += xv.x*a0.z; acc.w += xv.x*a0.w;
        acc.x += xv.y*a1.x; acc.y += xv.y*a1.y; acc.z += xv.y*a1.z; acc.w += xv.y*a1.w;
        acc.x += xv.z*a2.x; acc.y += xv.z*a2.y; acc.z += xv.z*a2.z; acc.w += xv.z*a2.w;
        acc.x += xv.w*a3.x; acc.y += xv.w*a3.y; acc.z += xv.w*a3.z; acc.w += xv.w*a3.w;
      }
    }
    *(float4*)(part + kc*C + o4*4) = acc;
  }
  __syncthreads();
}

// ---- encoder tiled GEMM stage (unchanged) ----
static __device__ void gemm_stage(const float* __restrict__ A, const float* __restrict__ W,
                                  const float* __restrict__ bias, const float* __restrict__ res,
                                  float* __restrict__ out, int R, int C, int K, int relu,
                                  float* sA) {
  const int t = threadIdx.x;
  const bool act = (t < 256);
  const int lane = t & 63, wv = (t >> 6) & 3;
  const int ntc = C >> 6;
  const int ntiles = (R >> 5) * ntc;
  for (int tile = blockIdx.x; tile < ntiles; tile += gridDim.x) {
    const int tr = tile / ntc, tc = tile - tr*ntc;
    const int r0 = tr << 5;
    const int c  = (tc << 6) + lane;
    float acc[8] = {0,0,0,0,0,0,0,0};
    for (int kc = 0; kc < K; kc += 256) {
      __syncthreads();
      if (act) {
#pragma unroll
        for (int u = 0; u < 8; u++) {
          int idx = u*256 + t;
          int rr = idx >> 6, cc = idx & 63;
          ((float4*)sA)[idx] = *(const float4*)(A + (r0+rr)*K + kc + cc*4);
        }
      }
      __syncthreads();
      if (act) {
        const float* wr = W + c*K + kc;
        for (int k = 0; k < 256; k += 4) {
          float4 w4 = *(const float4*)(wr + k);
#pragma unroll
          for (int r = 0; r < 8; r++) {
            float4 a4 = *(const float4*)(sA + (wv*8 + r)*256 + k);
            acc[r] += a4.x*w4.x; acc[r] += a4.y*w4.y; acc[r] += a4.z*w4.z; acc[r] += a4.w*w4.w;
          }
        }
      }
    }
    if (act) {
      float bb = bias ? bias[c] : 0.0f;
#pragma unroll
      for (int r = 0; r < 8; r++) {
        int row = r0 + wv*8 + r;
        float v = acc[r] + bb;
        if (relu) v = fmaxf(v, 0.0f);
        if (res)  v += res[row*C + c];
        out[row*C + c] = v;
      }
    }
  }
}

// ---- encoder LN stage ----
static __device__ void ln_stage(const float* in, const float* lw, const float* lb,
                                float* out, int R) {
  const int lane = threadIdx.x & 63;
  int gw = blockIdx.x*8 + (threadIdx.x >> 6);
  for (int row = gw; row < R; row += gridDim.x*8) {
    const float* ir = in + row*256;
    float x0 = ir[lane], x1 = ir[lane+64], x2 = ir[lane+128], x3 = ir[lane+192];
    float s = (x0 + x1) + (x2 + x3);
#pragma unroll
    for (int m = 1; m < 64; m <<= 1) s += __shfl_xor(s, m);
    float mean = s * 0.00390625f;
    float d0 = x0-mean, d1 = x1-mean, d2 = x2-mean, d3 = x3-mean;
    float q = (d0*d0 + d1*d1) + (d2*d2 + d3*d3);
#pragma unroll
    for (int m = 1; m < 64; m <<= 1) q += __shfl_xor(q, m);
    float rs = 1.0f / sqrtf(q * 0.00390625f + 1e-5f);
    float* orow = out + row*256;
    orow[lane]     = d0*rs*lw[lane]     + lb[lane];
    orow[lane+64]  = d1*rs*lw[lane+64]  + lb[lane+64];
    orow[lane+128] = d2*rs*lw[lane+128] + lb[lane+128];
    orow[lane+192] = d3*rs*lw[lane+192] + lb[lane+192];
  }
}

// ---- encoder attention core (unchanged; K rows in [p][d] layout) ----
static __device__ void attn_core(const float* qd, const float* kb, const float* vb,
                                 int krstride, int kstride, int nk,
                                 float* sc, float* red, float* ao) {
  const int t = threadIdx.x;
  const int r = t >> 5, p0 = t & 31;
  const bool act = (t < 256);
  if (act) {
#pragma unroll
    for (int pass = 0; pass < 2; pass++) {
      int p = pass*32 + p0;
      if (p < nk) {
        const float4* k4 = (const float4*)(kb + r*krstride + p*kstride);
        const float4* q4 = (const float4*)(qd + r*32);
        float a = 0.0f;
#pragma unroll
        for (int d4 = 0; d4 < 8; d4++) {
          float4 kv = k4[d4], qv = q4[d4];
          a += qv.x*kv.x; a += qv.y*kv.y; a += qv.z*kv.z; a += qv.w*kv.w;
        }
        sc[r*48 + p] = a * 0.17677669529663687f;
      }
    }
  }
  __syncthreads();
  if (t < 8) {
    float m = sc[t*48];
    for (int p = 1; p < nk; p++) m = fmaxf(m, sc[t*48 + p]);
    red[t] = m;
  }
  __syncthreads();
  if (act) {
#pragma unroll
    for (int pass = 0; pass < 2; pass++) {
      int p = pass*32 + p0;
      if (p < nk) sc[r*48 + p] = expf(sc[r*48 + p] - red[r]);
    }
  }
  __syncthreads();
  if (t < 8) {
    float s = 0.0f;
    for (int p = 0; p < nk; p++) s += sc[t*48 + p];
    red[8 + t] = s;
  }
  __syncthreads();
  if (act) {
#pragma unroll
    for (int pass = 0; pass < 2; pass++) {
      int p = pass*32 + p0;
      if (p < nk) sc[r*48 + p] = sc[r*48 + p] / red[8 + r];
    }
  }
  __syncthreads();
  if (act) {
    const int d2 = t & 31;
    const float* vr = vb + r*krstride + d2;
    float a = 0.0f;
    for (int p = 0; p < nk; p++) a += sc[r*48 + p] * vr[p*kstride];
    ao[r*32 + d2] = a;
  }
  __syncthreads();
}

static __device__ void enc_attn_stage(const float* QKV, float* AO, float* sm) {
  const int t = threadIdx.x;
  const bool act = (t < 256);
  float* qd  = sm;
  float* sc  = sm + 256;
  float* ao  = sm + 640;
  float* red = sm + 896;
  for (int pi = blockIdx.x; pi < 512; pi += gridDim.x) {
    int b = pi >> 3, h = pi & 7;
    const float* Qb = QKV + b*48*768 + h*32;
    const float* Kb = QKV + b*48*768 + 256 + h*32;
    const float* Vb = QKV + b*48*768 + 512 + h*32;
    for (int qg = 0; qg < 6; qg++) {
      if (act) { int r = t >> 5, d2 = t & 31; qd[r*32 + d2] = Qb[(qg*8 + r)*768 + d2]; }
      __syncthreads();
      attn_core(qd, Kb, Vb, 0, 768, 48, sc, red, ao);
      if (act) { int r = t >> 5, d2 = t & 31; AO[(b*48 + qg*8 + r)*256 + h*32 + d2] = ao[r*32 + d2]; }
      __syncthreads();
    }
  }
}

// ---- decode attention: K transposed [d4][p][4] (coalesced over p); V in [p][d] ----
// PV loop batch-loads 8 V rows ahead (independent addresses) then consumes in
// strictly ascending p order -> accumulation order unchanged.
static __device__ void attn_dec(const float* qd, const float* kt, const float* v,
                                int nk, float* sc, float* red, float* ao) {
  const int t = threadIdx.x;
  const int r = t >> 5, p0 = t & 31;
  const bool act = (t < 256);
  if (act) {
    const float4* q4 = (const float4*)(qd + r*32);
#pragma unroll
    for (int pass = 0; pass < 2; pass++) {
      int p = pass*32 + p0;
      if (p < nk) {
        const float* kb = kt + r*1536 + p*4;   // r = head; 8 d4-blocks of 192 floats
        float a = 0.0f;
#pragma unroll
        for (int j = 0; j < 8; j++) {
          float4 kv = *(const float4*)(kb + j*192);
          float4 qv = q4[j];
          a += qv.x*kv.x; a += qv.y*kv.y; a += qv.z*kv.z; a += qv.w*kv.w;
        }
        sc[r*48 + p] = a * 0.17677669529663687f;
      }
    }
  }
  __syncthreads();
  if (t < 8) {
    float m = sc[t*48];
    for (int p = 1; p < nk; p++) m = fmaxf(m, sc[t*48 + p]);
    red[t] = m;
  }
  __syncthreads();
  if (act) {
#pragma unroll
    for (int pass = 0; pass < 2; pass++) {
      int p = pass*32 + p0;
      if (p < nk) sc[r*48 + p] = expf(sc[r*48 + p] - red[r]);
    }
  }
  __syncthreads();
  if (t < 8) {
    float s = 0.0f;
    for (int p = 0; p < nk; p++) s += sc[t*48 + p];
    red[8 + t] = s;
  }
  __syncthreads();
  if (act) {
#pragma unroll
    for (int pass = 0; pass < 2; pass++) {
      int p = pass*32 + p0;
      if (p < nk) sc[r*48 + p] = sc[r*48 + p] / red[8 + r];
    }
  }
  __syncthreads();
  if (act) {
    const int d2 = t & 31;
    const float* vr = v + r*32 + d2;
    float a = 0.0f;
    int p = 0;
    for (; p + 8 <= nk; p += 8) {
      float vv[8], ss[8];
#pragma unroll
      for (int j = 0; j < 8; j++) { vv[j] = vr[(p+j)*256]; ss[j] = sc[r*48 + p + j]; }
#pragma unroll
      for (int j = 0; j < 8; j++) a += ss[j] * vv[j];
    }
    for (; p < nk; p++) a += sc[r*48 + p] * vr[p*256];
    ao[r*32 + d2] = a;
  }
  __syncthreads();
}

// ================= the single persistent kernel =================
__global__ void __launch_bounds__(512)
genrev5_kernel(GParams P) {
  __shared__ float sm[8448];
  float* ws = P.ws;
  const int wg = blockIdx.x;
  const int t  = threadIdx.x;

  // ---- E0: encoder embeddings + pe ----
  if (t < 256) {
    for (int rr = 0; rr < 12; rr++) {
      int row = wg*12 + rr;
      int b = row / 48, s = row % 48;
      int tok = (s < 32) ? P.xc[b*32 + s] : P.xct[b*16 + (s - 32)];
      ws[X_OFF + row*256 + t] = P.emb[(s*1024 + tok)*256 + t] + pe_val(s, t);
    }
  }
  gbar(&g_cntA, &g_genA, 256);

  // ---- encoder: 6 post-norm layers ----
  float* Xp = ws + X_OFF;
  for (int l = 0; l < 6; l++) {
    gemm_stage(Xp, P.ewqkv + l*768*256, P.ebqkv + l*768, nullptr, ws + QKV_OFF, 3072, 768, 256, 0, sm);
    gbar(&g_cntA, &g_genA, 256);
    enc_attn_stage(ws + QKV_OFF, ws + AO_OFF, sm);
    gbar(&g_cntA, &g_genA, 256);
    gemm_stage(ws + AO_OFF, P.ewo + l*256*256, P.ebo + l*256, Xp, ws + RES1_OFF, 3072, 256, 256, 0, sm);
    gbar(&g_cntA, &g_genA, 256);
    ln_stage(ws + RES1_OFF, P.elnw + (l*2 + 0)*256, P.elnb + (l*2 + 0)*256, ws + X1_OFF, 3072);
    gbar(&g_cntA, &g_genA, 256);
    gemm_stage(ws + X1_OFF, P.ew1 + l*1024*256, P.eb1 + l*1024, nullptr, ws + HB_OFF, 3072, 1024, 256, 1, sm);
    gbar(&g_cntA, &g_genA, 256);
    gemm_stage(ws + HB_OFF, P.ew2 + l*256*1024, P.eb2 + l*256, ws + X1_OFF, ws + RES2_OFF, 3072, 256, 1024, 0, sm);
    gbar(&g_cntA, &g_genA, 256);
    ln_stage(ws + RES2_OFF, P.elnw + (l*2 + 1)*256, P.elnb + (l*2 + 1)*256, Xp, 3072);
    gbar(&g_cntA, &g_genA, 256);
  }
  ln_stage(Xp, P.lnfw, P.lnfb, ws + MEM_OFF, 3072);
  gbar(&g_cntA, &g_genA, 256);
  // cross K (plain, temp at PCK) and cross V (final layout) for all 6 layers
  for (int l = 0; l < 6; l++) {
    gemm_stage(ws + MEM_OFF, P.cwqkv + (l*768 + 256)*256, P.cbqkv + l*768 + 256, nullptr,
               ws + PCK_OFF + l*786432, 3072, 256, 256, 0, sm);
    gemm_stage(ws + MEM_OFF, P.cwqkv + (l*768 + 512)*256, P.cbqkv + l*768 + 512, nullptr,
               ws + CV_OFF + l*786432, 3072, 256, 256, 0, sm);
  }
  gbar(&g_cntA, &g_genA, 256);

  // ---- transpose phase: decode weights -> [k][o]; plain cross-K -> [d4][p][4] ----
  {
    const int gt = wg*512 + t;
    const int GT = 256*512;
    for (int idx = gt; idx < 6*256*768; idx += GT) {
      int l = idx / 196608, r = idx - l*196608;
      int k = r / 768, o = r - k*768;
      ws[SWQKVT + idx] = P.swqkv[(l*768 + o)*256 + k];
    }
    for (int idx = gt; idx < 6*65536; idx += GT) {
      int l = idx >> 16, r = idx & 65535, k = r >> 8, o = r & 255;
      ws[SWOT + idx] = P.swo[(l*256 + o)*256 + k];
    }
    for (int idx = gt; idx < 6*65536; idx += GT) {
      int l = idx >> 16, r = idx & 65535, k = r >> 8, o = r & 255;
      ws[CWQT + idx] = P.cwqkv[(l*768 + o)*256 + k];
    }
    for (int idx = gt; idx < 6*65536; idx += GT) {
      int l = idx >> 16, r = idx & 65535, k = r >> 8, o = r & 255;
      ws[CWOT + idx] = P.cwo[(l*256 + o)*256 + k];
    }
    for (int idx = gt; idx < 6*262144; idx += GT) {
      int l = idx >> 18, r = idx & 262143, k = r >> 10, o = r & 1023;
      ws[DW1T + idx] = P.dw1[(l*1024 + o)*256 + k];
    }
    for (int idx = gt; idx < 6*262144; idx += GT) {
      int l = idx >> 18, r = idx & 262143, k = r >> 8, o = r & 255;
      ws[DW2T + idx] = P.dw2[(l*256 + o)*1024 + k];
    }
    // CKT[l][b][d4][p][c] from plain CK[l][b*48+p][d]
    for (int idx = gt; idx < 6*64*48*256; idx += GT) {
      int l = idx / 786432, r = idx - l*786432;
      int b = r / 12288, q = r - b*12288;
      int d4 = q / 192, s2 = q - d4*192;
      int p = s2 >> 2, c = s2 & 3;
      ws[CKT_OFF + idx] = ws[PCK_OFF + l*786432 + (b*48 + p)*256 + d4*4 + c];
    }
  }
  gbar(&g_cntA, &g_genA, 256);

  // ================= barrier-free per-row decode: WG b owns batch row b =================
  if (wg >= 64) return;
  const int b = wg;

  float* cur  = sm;           // 256
  float* qv   = sm + 256;     // 256
  float* av   = sm + 512;     // 256
  float* y1   = sm + 768;     // 256
  float* y2   = sm + 1024;    // 256
  float* hbf  = sm + 1280;    // 1024
  float* sc   = sm + 2304;    // 384
  float* red  = sm + 2688;    // 32
  float* y0   = sm + 2720;    // 256
  float* bvv  = sm + 2976;    // 256
  int*   bii  = (int*)(sm + 3232); // 256
  float* part = sm + 3488;    // 2048

  if (t < 256) y0[t] = P.sos[t] + pe_val(0, t);
  __syncthreads();

  for (int i = 0; i < 48; i++) {
    if (t < 256) cur[t] = y0[t];
    __syncthreads();
    for (int l = 0; l < 6; l++) {
      const int skt = SKT_OFF + l*786432 + b*12288;
      const int sv  = SV_OFF  + l*786432 + b*12288;
      const int ckt = CKT_OFF + l*786432 + b*12288;
      const int cv  = CV_OFF  + l*786432 + b*12288;
      // --- self QKV (transposed, coalesced, 2-way k-split) ---
      matvec_t<768,2,256>(ws + SWQKVT + l*196608, cur, part);
      for (int o = t; o < 768; o += 512) {
        float v = part[o] + part[768 + o] + P.sbqkv[l*768 + o];
        if (o < 256)      qv[o] = v;
        else if (o < 512) { int d = o - 256; ws[skt + (d>>2)*192 + i*4 + (d&3)] = v; }
        else              ws[sv + i*256 + (o - 512)] = v;
      }
      __syncthreads();
      attn_dec(qv, ws + skt, ws + sv, i + 1, sc, red, av);
      // --- self out-proj + residual + LN ---
      matvec_t<256,8,256>(ws + SWOT + l*65536, av, part);
      if (t < 256) {
        float s = part[t];
#pragma unroll
        for (int kc = 1; kc < 8; kc++) s += part[kc*256 + t];
        y1[t] = cur[t] + (s + P.sbo[l*256 + t]);
      }
      __syncthreads();
      if (t < 64) wave_ln_row(y1, P.dlnw + (l*3 + 0)*256, P.dlnb + (l*3 + 0)*256);
      __syncthreads();
      // --- cross q ---
      matvec_t<256,8,256>(ws + CWQT + l*65536, y1, part);
      if (t < 256) {
        float s = part[t];
#pragma unroll
        for (int kc = 1; kc < 8; kc++) s += part[kc*256 + t];
        qv[t] = s + P.cbqkv[l*768 + t];
      }
      __syncthreads();
      attn_dec(qv, ws + ckt, ws + cv, 48, sc, red, av);
      matvec_t<256,8,256>(ws + CWOT + l*65536, av, part);
      if (t < 256) {
        float s = part[t];
#pragma unroll
        for (int kc = 1; kc < 8; kc++) s += part[kc*256 + t];
        y2[t] = y1[t] + (s + P.cbo[l*256 + t]);
      }
      __syncthreads();
      if (t < 64) wave_ln_row(y2, P.dlnw + (l*3 + 1)*256, P.dlnb + (l*3 + 1)*256);
      __syncthreads();
      // --- FFN ---
      matvec_t<1024,2,256>(ws + DW1T + l*262144, y2, part);
      for (int o = t; o < 1024; o += 512)
        hbf[o] = fmaxf(part[o] + part[1024 + o] + P.db1[l*1024 + o], 0.0f);
      __syncthreads();
      matvec_t<256,8,1024>(ws + DW2T + l*262144, hbf, part);
      if (t < 256) {
        float s = part[t];
#pragma unroll
        for (int kc = 1; kc < 8; kc++) s += part[kc*256 + t];
        cur[t] = y2[t] + (s + P.db2[l*256 + t]);
      }
      __syncthreads();
      if (t < 64) wave_ln_row(cur, P.dlnw + (l*3 + 2)*256, P.dlnb + (l*3 + 2)*256);
      __syncthreads();
    }
    // --- final LN (lnf[1]) ---
    if (t < 64) wave_ln_row(cur, P.lnfw + 256, P.lnfb + 256);
    __syncthreads();
    // --- head: wave-cooperative rows (coalesced 1 KB/row, xor-tree reduce) ---
    {
      const int wv = t >> 6, lane = t & 63;
      const float4 x4 = *(const float4*)(cur + lane*4);
      for (int base = 0; base < 1024; base += 16) {
        int o = base + wv, o2 = o + 8;
        float4 wa = *(const float4*)(P.hw + (size_t)(i*1024 + o)*256 + lane*4);
        float4 wb = *(const float4*)(P.hw + (size_t)(i*1024 + o2)*256 + lane*4);
        float sa = wa.x*x4.x; sa += wa.y*x4.y; sa += wa.z*x4.z; sa += wa.w*x4.w;
        float sb = wb.x*x4.x; sb += wb.y*x4.y; sb += wb.z*x4.z; sb += wb.w*x4.w;
#pragma unroll
        for (int m = 1; m < 64; m <<= 1) { sa += __shfl_xor(sa, m); sb += __shfl_xor(sb, m); }
        if (lane == 0) {
          hbf[o]  = sa + P.hb[i*1024 + o];
          hbf[o2] = sb + P.hb[i*1024 + o2];
        }
      }
    }
    __syncthreads();
    for (int o = t; o < 1024; o += 512)
      P.out[3072 + i*65536 + b*1024 + o] = hbf[o];
    __syncthreads();
    // --- gumbel-argmax sampling ---
    unsigned k0, k1;
    step_key(i, k0, k1);
    if (t < 256) {
      float bestv = -INFINITY; int besti = 0;
#pragma unroll
      for (int e = 0; e < 4; e++) {
        int v = t*4 + e;
        unsigned bits = gumbel_bits(k0, k1, b, v);
        float f = __uint_as_float((bits >> 9) | 0x3f800000u);
        float u = fmaxf(f - 1.0f, 1.17549435e-38f);
        float g = -logf(-logf(u));
        float z = g + hbf[v] / 0.1f;
        if (z > bestv) { bestv = z; besti = v; }
      }
      bvv[t] = bestv; bii[t] = besti;
    }
    __syncthreads();
    for (int s = 128; s > 0; s >>= 1) {
      if (t < s) {
        float ov = bvv[t+s]; int oi = bii[t+s];
        if (ov > bvv[t] || (ov == bvv[t] && oi < bii[t])) { bvv[t] = ov; bii[t] = oi; }
      }
      __syncthreads();
    }
    const int ch = bii[0];
    if (t == 0) {
      if (i < 32) P.out[b*32 + i] = (float)ch;
      else        P.out[2048 + b*16 + (i - 32)] = (float)ch;
    }
    if (t < 256) y0[t] = P.emb[(i*1024 + ch)*256 + t] + pe_val(i + 1, t);
    __syncthreads();
  }
}

extern "C" void kernel_launch(void* const* d_in, const int* in_sizes, int n_in,
                              void* d_out, int out_size, void* d_ws, size_t ws_size,
                              hipStream_t stream) {
  (void)in_sizes; (void)n_in; (void)out_size; (void)ws_size;
  GParams p;
  p.xc    = (const int*)  d_in[0];
  p.xct   = (const int*)  d_in[1];
  p.sos   = (const float*)d_in[2];
  p.emb   = (const float*)d_in[3];
  p.hw    = (const float*)d_in[4];
  p.hb    = (const float*)d_in[5];
  p.ewqkv = (const float*)d_in[6];
  p.ebqkv = (const float*)d_in[7];
  p.ewo   = (const float*)d_in[8];
  p.ebo   = (const float*)d_in[9];
  p.ew1   = (const float*)d_in[10];
  p.eb1   = (const float*)d_in[11];
  p.ew2   = (const float*)d_in[12];
  p.eb2   = (const float*)d_in[13];
  p.elnw  = (const float*)d_in[14];
  p.elnb  = (const float*)d_in[15];
  p.swqkv = (const float*)d_in[16];
  p.sbqkv = (const float*)d_in[17];
  p.swo   = (const float*)d_in[18];
  p.sbo   = (const float*)d_in[19];
  p.cwqkv = (const float*)d_in[20];
  p.cbqkv = (const float*)d_in[21];
  p.cwo   = (const float*)d_in[22];
  p.cbo   = (const float*)d_in[23];
  p.dw1   = (const float*)d_in[24];
  p.db1   = (const float*)d_in[25];
  p.dw2   = (const float*)d_in[26];
  p.db2   = (const float*)d_in[27];
  p.dlnw  = (const float*)d_in[28];
  p.dlnb  = (const float*)d_in[29];
  p.lnfw  = (const float*)d_in[30];
  p.lnfb  = (const float*)d_in[31];
  p.out   = (float*)d_out;
  p.ws    = (float*)d_ws;
  hipLaunchKernelGGL(genrev5_kernel, dim3(256), dim3(512), 0, stream, p);
}

// Round 3
// 23002.420 us; speedup vs baseline: 3.5458x; 1.0180x over previous
//
#include <hip/hip_runtime.h>
#include <math.h>

// ===== jax threefry mode: 1 = partitionable (jax >= 0.4.36 default) =====
#define JAX_PARTITIONABLE 1

// ---- model dims: NL=6 D=256 FF=1024 V=1024 S=48 BS=64 H=8 DH=32 ----

// ---- workspace layout (float offsets) ----
static constexpr int SWQKVT  = 0;                        // 6 x [256 k][768 o]
static constexpr int SWOT    = SWQKVT + 6*256*768;       // 1,179,648 ; 6 x [256][256]
static constexpr int CWQT    = SWOT   + 6*256*256;       // 1,572,864
static constexpr int CWOT    = CWQT   + 6*256*256;       // 1,966,080
static constexpr int DW1T    = CWOT   + 6*256*256;       // 2,359,296 ; 6 x [256][1024]
static constexpr int DW2T    = DW1T   + 6*256*1024;      // 3,932,160 ; 6 x [1024][256]
static constexpr int WT_END  = DW2T   + 6*1024*256;      // 5,505,024
static constexpr int CKT_OFF = WT_END;                   // 6 x 64 x [64 d4][48 p][4 c]
static constexpr int CV_OFF  = CKT_OFF + 6*64*48*256;    // 10,223,616 ; [l][b*48+p][256]
static constexpr int SKT_OFF = CV_OFF  + 6*64*48*256;    // 14,942,208
static constexpr int SV_OFF  = SKT_OFF + 6*64*48*256;    // 19,660,800
static constexpr int WS_END  = SV_OFF  + 6*64*48*256;    // 24,379,392 floats = 97.5 MB
// encoder-time aliases (dead before the regions' real use):
static constexpr int X_OFF    = 0;
static constexpr int MEM_OFF  = X_OFF + 3072*256;
static constexpr int QKV_OFF  = SKT_OFF;
static constexpr int AO_OFF   = QKV_OFF + 3072*768;
static constexpr int RES1_OFF = AO_OFF + 3072*256;
static constexpr int X1_OFF   = RES1_OFF + 3072*256;
static constexpr int HB_OFF   = SV_OFF;
static constexpr int RES2_OFF = HB_OFF + 3072*1024;
static constexpr int PCK_OFF  = SKT_OFF;
// ---- cohort soft-sync slots (relaxed-only, performance rendezvous) ----
// layout: [(i*7 + phase)][8 groups] ; phase 0..5 = layers, 6 = head. 2688 uints.
static constexpr int SSYNC_OFF = WS_END;                 // 3072 uints (12 KB)

struct GParams {
  const int   *xc, *xct;
  const float *sos, *emb, *hw, *hb;
  const float *ewqkv, *ebqkv, *ewo, *ebo, *ew1, *eb1, *ew2, *eb2, *elnw, *elnb;
  const float *swqkv, *sbqkv, *swo, *sbo;
  const float *cwqkv, *cbqkv, *cwo, *cbo;
  const float *dw1, *db1, *dw2, *db2, *dlnw, *dlnb, *lnfw, *lnfb;
  float *out;
  float *ws;
};

// ---- device-global barrier state (generation counters survive graph replays) ----
__device__ unsigned g_cntA = 0, g_genA = 0;

static __device__ __forceinline__ void gbar(unsigned* cnt, unsigned* gen, unsigned nb) {
  __syncthreads();
  if (threadIdx.x == 0) {
    __threadfence();
    unsigned g = __hip_atomic_load(gen, __ATOMIC_RELAXED, __HIP_MEMORY_SCOPE_AGENT);
    unsigned prev = __hip_atomic_fetch_add(cnt, 1u, __ATOMIC_ACQ_REL, __HIP_MEMORY_SCOPE_AGENT);
    if (prev == nb - 1u) {
      __hip_atomic_store(cnt, 0u, __ATOMIC_RELAXED, __HIP_MEMORY_SCOPE_AGENT);
      __threadfence();
      __hip_atomic_store(gen, g + 1u, __ATOMIC_RELEASE, __HIP_MEMORY_SCOPE_AGENT);
    } else {
      while (__hip_atomic_load(gen, __ATOMIC_ACQUIRE, __HIP_MEMORY_SCOPE_AGENT) == g)
        __builtin_amdgcn_s_sleep(1);
      __threadfence();
    }
  }
  __syncthreads();
}

// ---- cohort soft-sync: relaxed-only (NO fences, NO cache invalidation).
// Performance rendezvous for the 8 WGs sharing an XCD-L2 (wg % 8). All data
// consumed after this was made visible by the full gbar before decode; a
// timeout makes it untrusted-by-construction.
static __device__ __forceinline__ void cohort_sync(unsigned* slot) {
  __syncthreads();
  if (threadIdx.x == 0) {
    __hip_atomic_fetch_add(slot, 1u, __ATOMIC_RELAXED, __HIP_MEMORY_SCOPE_AGENT);
    for (int it = 0; it < 64; ++it) {
      if (__hip_atomic_load(slot, __ATOMIC_RELAXED, __HIP_MEMORY_SCOPE_AGENT) >= 8u) break;
      __builtin_amdgcn_s_sleep(1);
    }
  }
  __syncthreads();
}

// ---- threefry2x32 (exact jax rotation/key schedule) ----
static __device__ __forceinline__ void tf2x32(unsigned k0, unsigned k1, unsigned& x0, unsigned& x1) {
  unsigned ks2 = k0 ^ k1 ^ 0x1BD11BDAu;
  x0 += k0; x1 += k1;
#define TF_R(r) { x0 += x1; x1 = (x1 << r) | (x1 >> (32 - r)); x1 ^= x0; }
  TF_R(13) TF_R(15) TF_R(26) TF_R(6)   x0 += k1;  x1 += ks2 + 1u;
  TF_R(17) TF_R(29) TF_R(16) TF_R(24)  x0 += ks2; x1 += k0  + 2u;
  TF_R(13) TF_R(15) TF_R(26) TF_R(6)   x0 += k0;  x1 += k1  + 3u;
  TF_R(17) TF_R(29) TF_R(16) TF_R(24)  x0 += k1;  x1 += ks2 + 4u;
  TF_R(13) TF_R(15) TF_R(26) TF_R(6)   x0 += ks2; x1 += k0  + 5u;
#undef TF_R
}

static __device__ __forceinline__ void step_key(int i, unsigned& k0, unsigned& k1) {
#if JAX_PARTITIONABLE
  unsigned x0 = 0u, x1 = (unsigned)i;
  tf2x32(0u, 42u, x0, x1);
  k0 = x0; k1 = x1;
#else
  unsigned w[2];
  for (int wi = 0; wi < 2; wi++) {
    unsigned o = (unsigned)(2*i + wi), x0, x1;
    if (o < 48u) { x0 = o; x1 = 48u + o; tf2x32(0u, 42u, x0, x1); w[wi] = x0; }
    else         { x0 = o - 48u; x1 = o; tf2x32(0u, 42u, x0, x1); w[wi] = x1; }
  }
  k0 = w[0]; k1 = w[1];
#endif
}

static __device__ __forceinline__ unsigned gumbel_bits(unsigned k0, unsigned k1, int b, int v) {
#if JAX_PARTITIONABLE
  unsigned x0 = 0u, x1 = (unsigned)(b*1024 + v);
  tf2x32(k0, k1, x0, x1);
  return x0 ^ x1;
#else
  unsigned jj = (unsigned)((b & 31)*1024 + v);
  unsigned x0 = jj, x1 = 32768u + jj;
  tf2x32(k0, k1, x0, x1);
  return (b < 32) ? x0 : x1;
#endif
}

// ---- positional encoding element ----
static __device__ __forceinline__ float pe_val(int p, int c) {
  const float KC = (float)(-9.210340371976184 / 256.0);
  int j = c >> 1;
  float dv = expf((float)(2*j) * KC);
  float a = (float)p * dv;
  return (c & 1) ? cosf(a) : sinf(a);
}

// ---- per-wave LayerNorm of a 256-float LDS row (call with one full wave) ----
static __device__ __forceinline__ void wave_ln_row(float* row, const float* lw, const float* lb) {
  const int lane = threadIdx.x & 63;
  float x0 = row[lane], x1 = row[lane+64], x2 = row[lane+128], x3 = row[lane+192];
  float s = (x0 + x1) + (x2 + x3);
#pragma unroll
  for (int m = 1; m < 64; m <<= 1) s += __shfl_xor(s, m);
  float mean = s * 0.00390625f;
  float d0 = x0-mean, d1 = x1-mean, d2 = x2-mean, d3 = x3-mean;
  float q = (d0*d0 + d1*d1) + (d2*d2 + d3*d3);
#pragma unroll
  for (int m = 1; m < 64; m <<= 1) q += __shfl_xor(q, m);
  float rs = 1.0f / sqrtf(q * 0.00390625f + 1e-5f);
  row[lane]     = d0*rs*lw[lane]     + lb[lane];
  row[lane+64]  = d1*rs*lw[lane+64]  + lb[lane+64];
  row[lane+128] = d2*rs*lw[lane+128] + lb[lane+128];
  row[lane+192] = d3*rs*lw[lane+192] + lb[lane+192];
}

// ---- transposed coalesced matvec partials: wt is [K][C] (k-major), x in LDS ----
// 32-deep load batches (128 VGPRs in flight per thread); consumption strictly
// ascending k with the same xv-component/FMA pairing as the original -> per-output
// accumulation is bitwise identical; only load scheduling changes.
template<int C, int KS, int K>
static __device__ void matvec_t(const float* __restrict__ wt, const float* __restrict__ x,
                                float* __restrict__ part) {
  const int t = threadIdx.x;
  constexpr int O4 = C/4;
  constexpr int KC = K/KS;
  constexpr int BT = (KC < 32) ? KC : 32;
  if (t < O4*KS) {
    const int kc = t / O4, o4 = t - kc*O4;
    const int k0 = kc*KC;
    float4 acc = {0.f,0.f,0.f,0.f};
    const float* wp = wt + k0*C + o4*4;
    for (int kb = 0; kb < KC; kb += BT) {
      float4 w[BT];
#pragma unroll
      for (int j = 0; j < BT; j++) w[j] = *(const float4*)(wp + (kb + j)*C);
#pragma unroll
      for (int j4 = 0; j4 < BT/4; j4++) {
        float4 xv = *(const float4*)(x + k0 + kb + j4*4);
        float4 a0 = w[j4*4+0], a1 = w[j4*4+1], a2 = w[j4*4+2], a3 = w[j4*4+3];
        acc.x += xv.x*a0.x; acc.y += xv.x*a0.y; acc.z += xv.x*a0.z; acc.w += xv.x*a0.w;
        acc.x += xv.y*a1.x; acc.y += xv.y*a1.y; acc.z += xv.y*a1.z; acc.w += xv.y*a1.w;
        acc.x += xv.z*a2.x; acc.y += xv.z*a2.y; acc.z += xv.z*a2.z; acc.w += xv.z*a2.w;
        acc.x += xv.w*a3.x; acc.y += xv.w*a3.y; acc.z += xv.w*a3.z; acc.w += xv.w*a3.w;
      }
    }
    *(float4*)(part + kc*C + o4*4) = acc;
  }
  __syncthreads();
}

// ---- encoder tiled GEMM stage (unchanged) ----
static __device__ void gemm_stage(const float* __restrict__ A, const float* __restrict__ W,
                                  const float* __restrict__ bias, const float* __restrict__ res,
                                  float* __restrict__ out, int R, int C, int K, int relu,
                                  float* sA) {
  const int t = threadIdx.x;
  const bool act = (t < 256);
  const int lane = t & 63, wv = (t >> 6) & 3;
  const int ntc = C >> 6;
  const int ntiles = (R >> 5) * ntc;
  for (int tile = blockIdx.x; tile < ntiles; tile += gridDim.x) {
    const int tr = tile / ntc, tc = tile - tr*ntc;
    const int r0 = tr << 5;
    const int c  = (tc << 6) + lane;
    float acc[8] = {0,0,0,0,0,0,0,0};
    for (int kc = 0; kc < K; kc += 256) {
      __syncthreads();
      if (act) {
#pragma unroll
        for (int u = 0; u < 8; u++) {
          int idx = u*256 + t;
          int rr = idx >> 6, cc = idx & 63;
          ((float4*)sA)[idx] = *(const float4*)(A + (r0+rr)*K + kc + cc*4);
        }
      }
      __syncthreads();
      if (act) {
        const float* wr = W + c*K + kc;
        for (int k = 0; k < 256; k += 4) {
          float4 w4 = *(const float4*)(wr + k);
#pragma unroll
          for (int r = 0; r < 8; r++) {
            float4 a4 = *(const float4*)(sA + (wv*8 + r)*256 + k);
            acc[r] += a4.x*w4.x; acc[r] += a4.y*w4.y; acc[r] += a4.z*w4.z; acc[r] += a4.w*w4.w;
          }
        }
      }
    }
    if (act) {
      float bb = bias ? bias[c] : 0.0f;
#pragma unroll
      for (int r = 0; r < 8; r++) {
        int row = r0 + wv*8 + r;
        float v = acc[r] + bb;
        if (relu) v = fmaxf(v, 0.0f);
        if (res)  v += res[row*C + c];
        out[row*C + c] = v;
      }
    }
  }
}

// ---- encoder LN stage ----
static __device__ void ln_stage(const float* in, const float* lw, const float* lb,
                                float* out, int R) {
  const int lane = threadIdx.x & 63;
  int gw = blockIdx.x*8 + (threadIdx.x >> 6);
  for (int row = gw; row < R; row += gridDim.x*8) {
    const float* ir = in + row*256;
    float x0 = ir[lane], x1 = ir[lane+64], x2 = ir[lane+128], x3 = ir[lane+192];
    float s = (x0 + x1) + (x2 + x3);
#pragma unroll
    for (int m = 1; m < 64; m <<= 1) s += __shfl_xor(s, m);
    float mean = s * 0.00390625f;
    float d0 = x0-mean, d1 = x1-mean, d2 = x2-mean, d3 = x3-mean;
    float q = (d0*d0 + d1*d1) + (d2*d2 + d3*d3);
#pragma unroll
    for (int m = 1; m < 64; m <<= 1) q += __shfl_xor(q, m);
    float rs = 1.0f / sqrtf(q * 0.00390625f + 1e-5f);
    float* orow = out + row*256;
    orow[lane]     = d0*rs*lw[lane]     + lb[lane];
    orow[lane+64]  = d1*rs*lw[lane+64]  + lb[lane+64];
    orow[lane+128] = d2*rs*lw[lane+128] + lb[lane+128];
    orow[lane+192] = d3*rs*lw[lane+192] + lb[lane+192];
  }
}

// ---- encoder attention core (unchanged; K rows in [p][d] layout) ----
static __device__ void attn_core(const float* qd, const float* kb, const float* vb,
                                 int krstride, int kstride, int nk,
                                 float* sc, float* red, float* ao) {
  const int t = threadIdx.x;
  const int r = t >> 5, p0 = t & 31;
  const bool act = (t < 256);
  if (act) {
#pragma unroll
    for (int pass = 0; pass < 2; pass++) {
      int p = pass*32 + p0;
      if (p < nk) {
        const float4* k4 = (const float4*)(kb + r*krstride + p*kstride);
        const float4* q4 = (const float4*)(qd + r*32);
        float a = 0.0f;
#pragma unroll
        for (int d4 = 0; d4 < 8; d4++) {
          float4 kv = k4[d4], qv = q4[d4];
          a += qv.x*kv.x; a += qv.y*kv.y; a += qv.z*kv.z; a += qv.w*kv.w;
        }
        sc[r*48 + p] = a * 0.17677669529663687f;
      }
    }
  }
  __syncthreads();
  if (t < 8) {
    float m = sc[t*48];
    for (int p = 1; p < nk; p++) m = fmaxf(m, sc[t*48 + p]);
    red[t] = m;
  }
  __syncthreads();
  if (act) {
#pragma unroll
    for (int pass = 0; pass < 2; pass++) {
      int p = pass*32 + p0;
      if (p < nk) sc[r*48 + p] = expf(sc[r*48 + p] - red[r]);
    }
  }
  __syncthreads();
  if (t < 8) {
    float s = 0.0f;
    for (int p = 0; p < nk; p++) s += sc[t*48 + p];
    red[8 + t] = s;
  }
  __syncthreads();
  if (act) {
#pragma unroll
    for (int pass = 0; pass < 2; pass++) {
      int p = pass*32 + p0;
      if (p < nk) sc[r*48 + p] = sc[r*48 + p] / red[8 + r];
    }
  }
  __syncthreads();
  if (act) {
    const int d2 = t & 31;
    const float* vr = vb + r*krstride + d2;
    float a = 0.0f;
    for (int p = 0; p < nk; p++) a += sc[r*48 + p] * vr[p*kstride];
    ao[r*32 + d2] = a;
  }
  __syncthreads();
}

static __device__ void enc_attn_stage(const float* QKV, float* AO, float* sm) {
  const int t = threadIdx.x;
  const bool act = (t < 256);
  float* qd  = sm;
  float* sc  = sm + 256;
  float* ao  = sm + 640;
  float* red = sm + 896;
  for (int pi = blockIdx.x; pi < 512; pi += gridDim.x) {
    int b = pi >> 3, h = pi & 7;
    const float* Qb = QKV + b*48*768 + h*32;
    const float* Kb = QKV + b*48*768 + 256 + h*32;
    const float* Vb = QKV + b*48*768 + 512 + h*32;
    for (int qg = 0; qg < 6; qg++) {
      if (act) { int r = t >> 5, d2 = t & 31; qd[r*32 + d2] = Qb[(qg*8 + r)*768 + d2]; }
      __syncthreads();
      attn_core(qd, Kb, Vb, 0, 768, 48, sc, red, ao);
      if (act) { int r = t >> 5, d2 = t & 31; AO[(b*48 + qg*8 + r)*256 + h*32 + d2] = ao[r*32 + d2]; }
      __syncthreads();
    }
  }
}

// ---- decode attention: K transposed [d4][p][4] (coalesced over p); V in [p][d] ----
// max/sum reductions batch-load 8 ahead; fmax is order-insensitive, the sum keeps
// strictly ascending p order (bitwise identical). PV keeps ascending-p accumulation.
static __device__ void attn_dec(const float* qd, const float* kt, const float* v,
                                int nk, float* sc, float* red, float* ao) {
  const int t = threadIdx.x;
  const int r = t >> 5, p0 = t & 31;
  const bool act = (t < 256);
  if (act) {
    const float4* q4 = (const float4*)(qd + r*32);
#pragma unroll
    for (int pass = 0; pass < 2; pass++) {
      int p = pass*32 + p0;
      if (p < nk) {
        const float* kb = kt + r*1536 + p*4;   // r = head; 8 d4-blocks of 192 floats
        float a = 0.0f;
#pragma unroll
        for (int j = 0; j < 8; j++) {
          float4 kv = *(const float4*)(kb + j*192);
          float4 qv = q4[j];
          a += qv.x*kv.x; a += qv.y*kv.y; a += qv.z*kv.z; a += qv.w*kv.w;
        }
        sc[r*48 + p] = a * 0.17677669529663687f;
      }
    }
  }
  __syncthreads();
  if (t < 8) {
    const float* scr = sc + t*48;
    float m = scr[0];
    int p = 1;
    for (; p + 8 <= nk; p += 8) {
      float s0=scr[p],s1=scr[p+1],s2=scr[p+2],s3=scr[p+3],
            s4=scr[p+4],s5=scr[p+5],s6=scr[p+6],s7=scr[p+7];
      m=fmaxf(m,s0); m=fmaxf(m,s1); m=fmaxf(m,s2); m=fmaxf(m,s3);
      m=fmaxf(m,s4); m=fmaxf(m,s5); m=fmaxf(m,s6); m=fmaxf(m,s7);
    }
    for (; p < nk; p++) m = fmaxf(m, scr[p]);
    red[t] = m;
  }
  __syncthreads();
  if (act) {
#pragma unroll
    for (int pass = 0; pass < 2; pass++) {
      int p = pass*32 + p0;
      if (p < nk) sc[r*48 + p] = expf(sc[r*48 + p] - red[r]);
    }
  }
  __syncthreads();
  if (t < 8) {
    const float* scr = sc + t*48;
    float s = 0.0f;
    int p = 0;
    for (; p + 8 <= nk; p += 8) {
      float s0=scr[p],s1=scr[p+1],s2=scr[p+2],s3=scr[p+3],
            s4=scr[p+4],s5=scr[p+5],s6=scr[p+6],s7=scr[p+7];
      s+=s0; s+=s1; s+=s2; s+=s3; s+=s4; s+=s5; s+=s6; s+=s7;
    }
    for (; p < nk; p++) s += scr[p];
    red[8 + t] = s;
  }
  __syncthreads();
  if (act) {
#pragma unroll
    for (int pass = 0; pass < 2; pass++) {
      int p = pass*32 + p0;
      if (p < nk) sc[r*48 + p] = sc[r*48 + p] / red[8 + r];
    }
  }
  __syncthreads();
  if (act) {
    const int d2 = t & 31;
    const float* vr = v + r*32 + d2;
    float a = 0.0f;
    int p = 0;
    for (; p + 8 <= nk; p += 8) {
      float vv[8], ss[8];
#pragma unroll
      for (int j = 0; j < 8; j++) { vv[j] = vr[(p+j)*256]; ss[j] = sc[r*48 + p + j]; }
#pragma unroll
      for (int j = 0; j < 8; j++) a += ss[j] * vv[j];
    }
    for (; p < nk; p++) a += sc[r*48 + p] * vr[p*256];
    ao[r*32 + d2] = a;
  }
  __syncthreads();
}

// ================= the single persistent kernel =================
__global__ void __launch_bounds__(512)
genrev6_kernel(GParams P) {
  __shared__ float sm[8448];
  float* ws = P.ws;
  const int wg = blockIdx.x;
  const int t  = threadIdx.x;

  // ---- E0: encoder embeddings + pe ----
  if (t < 256) {
    for (int rr = 0; rr < 12; rr++) {
      int row = wg*12 + rr;
      int b = row / 48, s = row % 48;
      int tok = (s < 32) ? P.xc[b*32 + s] : P.xct[b*16 + (s - 32)];
      ws[X_OFF + row*256 + t] = P.emb[(s*1024 + tok)*256 + t] + pe_val(s, t);
    }
  }
  gbar(&g_cntA, &g_genA, 256);

  // ---- encoder: 6 post-norm layers ----
  float* Xp = ws + X_OFF;
  for (int l = 0; l < 6; l++) {
    gemm_stage(Xp, P.ewqkv + l*768*256, P.ebqkv + l*768, nullptr, ws + QKV_OFF, 3072, 768, 256, 0, sm);
    gbar(&g_cntA, &g_genA, 256);
    enc_attn_stage(ws + QKV_OFF, ws + AO_OFF, sm);
    gbar(&g_cntA, &g_genA, 256);
    gemm_stage(ws + AO_OFF, P.ewo + l*256*256, P.ebo + l*256, Xp, ws + RES1_OFF, 3072, 256, 256, 0, sm);
    gbar(&g_cntA, &g_genA, 256);
    ln_stage(ws + RES1_OFF, P.elnw + (l*2 + 0)*256, P.elnb + (l*2 + 0)*256, ws + X1_OFF, 3072);
    gbar(&g_cntA, &g_genA, 256);
    gemm_stage(ws + X1_OFF, P.ew1 + l*1024*256, P.eb1 + l*1024, nullptr, ws + HB_OFF, 3072, 1024, 256, 1, sm);
    gbar(&g_cntA, &g_genA, 256);
    gemm_stage(ws + HB_OFF, P.ew2 + l*256*1024, P.eb2 + l*256, ws + X1_OFF, ws + RES2_OFF, 3072, 256, 1024, 0, sm);
    gbar(&g_cntA, &g_genA, 256);
    ln_stage(ws + RES2_OFF, P.elnw + (l*2 + 1)*256, P.elnb + (l*2 + 1)*256, Xp, 3072);
    gbar(&g_cntA, &g_genA, 256);
  }
  ln_stage(Xp, P.lnfw, P.lnfb, ws + MEM_OFF, 3072);
  gbar(&g_cntA, &g_genA, 256);
  // cross K (plain, temp at PCK) and cross V (final layout) for all 6 layers
  for (int l = 0; l < 6; l++) {
    gemm_stage(ws + MEM_OFF, P.cwqkv + (l*768 + 256)*256, P.cbqkv + l*768 + 256, nullptr,
               ws + PCK_OFF + l*786432, 3072, 256, 256, 0, sm);
    gemm_stage(ws + MEM_OFF, P.cwqkv + (l*768 + 512)*256, P.cbqkv + l*768 + 512, nullptr,
               ws + CV_OFF + l*786432, 3072, 256, 256, 0, sm);
  }
  gbar(&g_cntA, &g_genA, 256);

  // ---- transpose phase: decode weights -> [k][o]; plain cross-K -> [d4][p][4] ----
  {
    const int gt = wg*512 + t;
    const int GT = 256*512;
    for (int idx = gt; idx < 6*256*768; idx += GT) {
      int l = idx / 196608, r = idx - l*196608;
      int k = r / 768, o = r - k*768;
      ws[SWQKVT + idx] = P.swqkv[(l*768 + o)*256 + k];
    }
    for (int idx = gt; idx < 6*65536; idx += GT) {
      int l = idx >> 16, r = idx & 65535, k = r >> 8, o = r & 255;
      ws[SWOT + idx] = P.swo[(l*256 + o)*256 + k];
    }
    for (int idx = gt; idx < 6*65536; idx += GT) {
      int l = idx >> 16, r = idx & 65535, k = r >> 8, o = r & 255;
      ws[CWQT + idx] = P.cwqkv[(l*768 + o)*256 + k];
    }
    for (int idx = gt; idx < 6*65536; idx += GT) {
      int l = idx >> 16, r = idx & 65535, k = r >> 8, o = r & 255;
      ws[CWOT + idx] = P.cwo[(l*256 + o)*256 + k];
    }
    for (int idx = gt; idx < 6*262144; idx += GT) {
      int l = idx >> 18, r = idx & 262143, k = r >> 10, o = r & 1023;
      ws[DW1T + idx] = P.dw1[(l*1024 + o)*256 + k];
    }
    for (int idx = gt; idx < 6*262144; idx += GT) {
      int l = idx >> 18, r = idx & 262143, k = r >> 8, o = r & 255;
      ws[DW2T + idx] = P.dw2[(l*256 + o)*1024 + k];
    }
    // CKT[l][b][d4][p][c] from plain CK[l][b*48+p][d]
    for (int idx = gt; idx < 6*64*48*256; idx += GT) {
      int l = idx / 786432, r = idx - l*786432;
      int b = r / 12288, q = r - b*12288;
      int d4 = q / 192, s2 = q - d4*192;
      int p = s2 >> 2, c = s2 & 3;
      ws[CKT_OFF + idx] = ws[PCK_OFF + l*786432 + (b*48 + p)*256 + d4*4 + c];
    }
    // zero the cohort soft-sync slots (relaxed atomic stores -> LLC)
    unsigned* ssync = (unsigned*)(ws + SSYNC_OFF);
    for (int idx = gt; idx < 3072; idx += GT)
      __hip_atomic_store(&ssync[idx], 0u, __ATOMIC_RELAXED, __HIP_MEMORY_SCOPE_AGENT);
  }
  gbar(&g_cntA, &g_genA, 256);

  // ================= barrier-free per-row decode: WG b owns batch row b =================
  if (wg >= 64) return;
  const int b = wg;
  const int grp = wg & 7;      // round-robin dispatch: same grp -> same XCD-L2
  unsigned* ssync = (unsigned*)(ws + SSYNC_OFF);

  float* cur  = sm;           // 256
  float* qv   = sm + 256;     // 256
  float* av   = sm + 512;     // 256
  float* y1   = sm + 768;     // 256
  float* y2   = sm + 1024;    // 256
  float* hbf  = sm + 1280;    // 1024
  float* sc   = sm + 2304;    // 384
  float* red  = sm + 2688;    // 32
  float* y0   = sm + 2720;    // 256
  float* bvv  = sm + 2976;    // 256
  int*   bii  = (int*)(sm + 3232); // 256
  float* part = sm + 3488;    // 2048

  if (t < 256) y0[t] = P.sos[t] + pe_val(0, t);
  __syncthreads();

  for (int i = 0; i < 48; i++) {
    if (t < 256) cur[t] = y0[t];
    __syncthreads();
    for (int l = 0; l < 6; l++) {
      // keep the 8 same-XCD WGs inside the same layer window (weight L2 sharing)
      cohort_sync(ssync + (i*7 + l)*8 + grp);
      const int skt = SKT_OFF + l*786432 + b*12288;
      const int sv  = SV_OFF  + l*786432 + b*12288;
      const int ckt = CKT_OFF + l*786432 + b*12288;
      const int cv  = CV_OFF  + l*786432 + b*12288;
      // --- self QKV (transposed, coalesced, 2-way k-split) ---
      matvec_t<768,2,256>(ws + SWQKVT + l*196608, cur, part);
      for (int o = t; o < 768; o += 512) {
        float v = part[o] + part[768 + o] + P.sbqkv[l*768 + o];
        if (o < 256)      qv[o] = v;
        else if (o < 512) { int d = o - 256; ws[skt + (d>>2)*192 + i*4 + (d&3)] = v; }
        else              ws[sv + i*256 + (o - 512)] = v;
      }
      __syncthreads();
      attn_dec(qv, ws + skt, ws + sv, i + 1, sc, red, av);
      // --- self out-proj + residual + LN ---
      matvec_t<256,8,256>(ws + SWOT + l*65536, av, part);
      if (t < 256) {
        float s = part[t];
#pragma unroll
        for (int kc = 1; kc < 8; kc++) s += part[kc*256 + t];
        y1[t] = cur[t] + (s + P.sbo[l*256 + t]);
      }
      __syncthreads();
      if (t < 64) wave_ln_row(y1, P.dlnw + (l*3 + 0)*256, P.dlnb + (l*3 + 0)*256);
      __syncthreads();
      // --- cross q ---
      matvec_t<256,8,256>(ws + CWQT + l*65536, y1, part);
      if (t < 256) {
        float s = part[t];
#pragma unroll
        for (int kc = 1; kc < 8; kc++) s += part[kc*256 + t];
        qv[t] = s + P.cbqkv[l*768 + t];
      }
      __syncthreads();
      attn_dec(qv, ws + ckt, ws + cv, 48, sc, red, av);
      matvec_t<256,8,256>(ws + CWOT + l*65536, av, part);
      if (t < 256) {
        float s = part[t];
#pragma unroll
        for (int kc = 1; kc < 8; kc++) s += part[kc*256 + t];
        y2[t] = y1[t] + (s + P.cbo[l*256 + t]);
      }
      __syncthreads();
      if (t < 64) wave_ln_row(y2, P.dlnw + (l*3 + 1)*256, P.dlnb + (l*3 + 1)*256);
      __syncthreads();
      // --- FFN ---
      matvec_t<1024,2,256>(ws + DW1T + l*262144, y2, part);
      for (int o = t; o < 1024; o += 512)
        hbf[o] = fmaxf(part[o] + part[1024 + o] + P.db1[l*1024 + o], 0.0f);
      __syncthreads();
      matvec_t<256,8,1024>(ws + DW2T + l*262144, hbf, part);
      if (t < 256) {
        float s = part[t];
#pragma unroll
        for (int kc = 1; kc < 8; kc++) s += part[kc*256 + t];
        cur[t] = y2[t] + (s + P.db2[l*256 + t]);
      }
      __syncthreads();
      if (t < 64) wave_ln_row(cur, P.dlnw + (l*3 + 2)*256, P.dlnb + (l*3 + 2)*256);
      __syncthreads();
    }
    // --- final LN (lnf[1]) ---
    if (t < 64) wave_ln_row(cur, P.lnfw + 256, P.lnfb + 256);
    __syncthreads();
    // --- head: wave-cooperative rows (coalesced 1 KB/row, xor-tree reduce) ---
    cohort_sync(ssync + (i*7 + 6)*8 + grp);
    {
      const int wv = t >> 6, lane = t & 63;
      const float4 x4 = *(const float4*)(cur + lane*4);
#pragma unroll 4
      for (int base = 0; base < 1024; base += 16) {
        int o = base + wv, o2 = o + 8;
        float4 wa = *(const float4*)(P.hw + (size_t)(i*1024 + o)*256 + lane*4);
        float4 wb = *(const float4*)(P.hw + (size_t)(i*1024 + o2)*256 + lane*4);
        float sa = wa.x*x4.x; sa += wa.y*x4.y; sa += wa.z*x4.z; sa += wa.w*x4.w;
        float sb = wb.x*x4.x; sb += wb.y*x4.y; sb += wb.z*x4.z; sb += wb.w*x4.w;
#pragma unroll
        for (int m = 1; m < 64; m <<= 1) { sa += __shfl_xor(sa, m); sb += __shfl_xor(sb, m); }
        if (lane == 0) {
          hbf[o]  = sa + P.hb[i*1024 + o];
          hbf[o2] = sb + P.hb[i*1024 + o2];
        }
      }
    }
    __syncthreads();
    for (int o = t; o < 1024; o += 512)
      P.out[3072 + i*65536 + b*1024 + o] = hbf[o];
    __syncthreads();
    // --- gumbel-argmax sampling ---
    unsigned k0, k1;
    step_key(i, k0, k1);
    if (t < 256) {
      float bestv = -INFINITY; int besti = 0;
#pragma unroll
      for (int e = 0; e < 4; e++) {
        int v = t*4 + e;
        unsigned bits = gumbel_bits(k0, k1, b, v);
        float f = __uint_as_float((bits >> 9) | 0x3f800000u);
        float u = fmaxf(f - 1.0f, 1.17549435e-38f);
        float g = -logf(-logf(u));
        float z = g + hbf[v] / 0.1f;
        if (z > bestv) { bestv = z; besti = v; }
      }
      bvv[t] = bestv; bii[t] = besti;
    }
    __syncthreads();
    for (int s = 128; s > 0; s >>= 1) {
      if (t < s) {
        float ov = bvv[t+s]; int oi = bii[t+s];
        if (ov > bvv[t] || (ov == bvv[t] && oi < bii[t])) { bvv[t] = ov; bii[t] = oi; }
      }
      __syncthreads();
    }
    const int ch = bii[0];
    if (t == 0) {
      if (i < 32) P.out[b*32 + i] = (float)ch;
      else        P.out[2048 + b*16 + (i - 32)] = (float)ch;
    }
    if (t < 256) y0[t] = P.emb[(i*1024 + ch)*256 + t] + pe_val(i + 1, t);
    __syncthreads();
  }
}

extern "C" void kernel_launch(void* const* d_in, const int* in_sizes, int n_in,
                              void* d_out, int out_size, void* d_ws, size_t ws_size,
                              hipStream_t stream) {
  (void)in_sizes; (void)n_in; (void)out_size; (void)ws_size;
  GParams p;
  p.xc    = (const int*)  d_in[0];
  p.xct   = (const int*)  d_in[1];
  p.sos   = (const float*)d_in[2];
  p.emb   = (const float*)d_in[3];
  p.hw    = (const float*)d_in[4];
  p.hb    = (const float*)d_in[5];
  p.ewqkv = (const float*)d_in[6];
  p.ebqkv = (const float*)d_in[7];
  p.ewo   = (const float*)d_in[8];
  p.ebo   = (const float*)d_in[9];
  p.ew1   = (const float*)d_in[10];
  p.eb1   = (const float*)d_in[11];
  p.ew2   = (const float*)d_in[12];
  p.eb2   = (const float*)d_in[13];
  p.elnw  = (const float*)d_in[14];
  p.elnb  = (const float*)d_in[15];
  p.swqkv = (const float*)d_in[16];
  p.sbqkv = (const float*)d_in[17];
  p.swo   = (const float*)d_in[18];
  p.sbo   = (const float*)d_in[19];
  p.cwqkv = (const float*)d_in[20];
  p.cbqkv = (const float*)d_in[21];
  p.cwo   = (const float*)d_in[22];
  p.cbo   = (const float*)d_in[23];
  p.dw1   = (const float*)d_in[24];
  p.db1   = (const float*)d_in[25];
  p.dw2   = (const float*)d_in[26];
  p.db2   = (const float*)d_in[27];
  p.dlnw  = (const float*)d_in[28];
  p.dlnb  = (const float*)d_in[29];
  p.lnfw  = (const float*)d_in[30];
  p.lnfb  = (const float*)d_in[31];
  p.out   = (float*)d_out;
  p.ws    = (float*)d_ws;
  hipLaunchKernelGGL(genrev6_kernel, dim3(256), dim3(512), 0, stream, p);
}

// Round 4
// 20278.482 us; speedup vs baseline: 4.0221x; 1.1343x over previous
//
#include <hip/hip_runtime.h>
#include <math.h>

// ===== jax threefry mode: 1 = partitionable (jax >= 0.4.36 default) =====
#define JAX_PARTITIONABLE 1

// ---- model dims: NL=6 D=256 FF=1024 V=1024 S=48 BS=64 H=8 DH=32 ----

// ---- workspace layout (float offsets) ----
static constexpr int SWQKVT  = 0;                        // 6 x [256 k][768 o]
static constexpr int SWOT    = SWQKVT + 6*256*768;       // 1,179,648 ; 6 x [256][256]
static constexpr int CWQT    = SWOT   + 6*256*256;       // 1,572,864
static constexpr int CWOT    = CWQT   + 6*256*256;       // 1,966,080
static constexpr int DW1T    = CWOT   + 6*256*256;       // 2,359,296 ; 6 x [256][1024]
static constexpr int DW2T    = DW1T   + 6*256*1024;      // 3,932,160 ; 6 x [1024][256]
static constexpr int WT_END  = DW2T   + 6*1024*256;      // 5,505,024
static constexpr int CKT_OFF = WT_END;                   // 6 x 64 x [64 d4][48 p][4 c]
static constexpr int CV_OFF  = CKT_OFF + 6*64*48*256;    // 10,223,616 ; [l][b*48+p][256]
static constexpr int SKT_OFF = CV_OFF  + 6*64*48*256;    // 14,942,208
static constexpr int SV_OFF  = SKT_OFF + 6*64*48*256;    // 19,660,800
static constexpr int WS_END  = SV_OFF  + 6*64*48*256;    // 24,379,392 floats = 97.5 MB
// encoder-time aliases (dead before the regions' real use):
static constexpr int X_OFF    = 0;
static constexpr int MEM_OFF  = X_OFF + 3072*256;
static constexpr int QKV_OFF  = SKT_OFF;
static constexpr int AO_OFF   = QKV_OFF + 3072*768;
static constexpr int RES1_OFF = AO_OFF + 3072*256;
static constexpr int X1_OFF   = RES1_OFF + 3072*256;
static constexpr int HB_OFF   = SV_OFF;
static constexpr int RES2_OFF = HB_OFF + 3072*1024;
static constexpr int PCK_OFF  = SKT_OFF;
// ---- cohort soft-sync slots (relaxed-only, performance rendezvous) ----
static constexpr int SSYNC_OFF = WS_END;                 // 3072 uints (12 KB)

struct GParams {
  const int   *xc, *xct;
  const float *sos, *emb, *hw, *hb;
  const float *ewqkv, *ebqkv, *ewo, *ebo, *ew1, *eb1, *ew2, *eb2, *elnw, *elnb;
  const float *swqkv, *sbqkv, *swo, *sbo;
  const float *cwqkv, *cbqkv, *cwo, *cbo;
  const float *dw1, *db1, *dw2, *db2, *dlnw, *dlnb, *lnfw, *lnfb;
  float *out;
  float *ws;
};

// ---- device-global barrier state (generation counters survive graph replays) ----
__device__ unsigned g_cntA = 0, g_genA = 0;

static __device__ __forceinline__ void gbar(unsigned* cnt, unsigned* gen, unsigned nb) {
  __syncthreads();
  if (threadIdx.x == 0) {
    __threadfence();
    unsigned g = __hip_atomic_load(gen, __ATOMIC_RELAXED, __HIP_MEMORY_SCOPE_AGENT);
    unsigned prev = __hip_atomic_fetch_add(cnt, 1u, __ATOMIC_ACQ_REL, __HIP_MEMORY_SCOPE_AGENT);
    if (prev == nb - 1u) {
      __hip_atomic_store(cnt, 0u, __ATOMIC_RELAXED, __HIP_MEMORY_SCOPE_AGENT);
      __threadfence();
      __hip_atomic_store(gen, g + 1u, __ATOMIC_RELEASE, __HIP_MEMORY_SCOPE_AGENT);
    } else {
      while (__hip_atomic_load(gen, __ATOMIC_ACQUIRE, __HIP_MEMORY_SCOPE_AGENT) == g)
        __builtin_amdgcn_s_sleep(1);
      __threadfence();
    }
  }
  __syncthreads();
}

// ---- cohort soft-sync: relaxed-only (NO fences, NO cache invalidation).
static __device__ __forceinline__ void cohort_sync(unsigned* slot) {
  __syncthreads();
  if (threadIdx.x == 0) {
    __hip_atomic_fetch_add(slot, 1u, __ATOMIC_RELAXED, __HIP_MEMORY_SCOPE_AGENT);
    for (int it = 0; it < 64; ++it) {
      if (__hip_atomic_load(slot, __ATOMIC_RELAXED, __HIP_MEMORY_SCOPE_AGENT) >= 8u) break;
      __builtin_amdgcn_s_sleep(1);
    }
  }
  __syncthreads();
}

// ---- threefry2x32 (exact jax rotation/key schedule) ----
static __device__ __forceinline__ void tf2x32(unsigned k0, unsigned k1, unsigned& x0, unsigned& x1) {
  unsigned ks2 = k0 ^ k1 ^ 0x1BD11BDAu;
  x0 += k0; x1 += k1;
#define TF_R(r) { x0 += x1; x1 = (x1 << r) | (x1 >> (32 - r)); x1 ^= x0; }
  TF_R(13) TF_R(15) TF_R(26) TF_R(6)   x0 += k1;  x1 += ks2 + 1u;
  TF_R(17) TF_R(29) TF_R(16) TF_R(24)  x0 += ks2; x1 += k0  + 2u;
  TF_R(13) TF_R(15) TF_R(26) TF_R(6)   x0 += k0;  x1 += k1  + 3u;
  TF_R(17) TF_R(29) TF_R(16) TF_R(24)  x0 += k1;  x1 += ks2 + 4u;
  TF_R(13) TF_R(15) TF_R(26) TF_R(6)   x0 += ks2; x1 += k0  + 5u;
#undef TF_R
}

static __device__ __forceinline__ void step_key(int i, unsigned& k0, unsigned& k1) {
#if JAX_PARTITIONABLE
  unsigned x0 = 0u, x1 = (unsigned)i;
  tf2x32(0u, 42u, x0, x1);
  k0 = x0; k1 = x1;
#else
  unsigned w[2];
  for (int wi = 0; wi < 2; wi++) {
    unsigned o = (unsigned)(2*i + wi), x0, x1;
    if (o < 48u) { x0 = o; x1 = 48u + o; tf2x32(0u, 42u, x0, x1); w[wi] = x0; }
    else         { x0 = o - 48u; x1 = o; tf2x32(0u, 42u, x0, x1); w[wi] = x1; }
  }
  k0 = w[0]; k1 = w[1];
#endif
}

static __device__ __forceinline__ unsigned gumbel_bits(unsigned k0, unsigned k1, int b, int v) {
#if JAX_PARTITIONABLE
  unsigned x0 = 0u, x1 = (unsigned)(b*1024 + v);
  tf2x32(k0, k1, x0, x1);
  return x0 ^ x1;
#else
  unsigned jj = (unsigned)((b & 31)*1024 + v);
  unsigned x0 = jj, x1 = 32768u + jj;
  tf2x32(k0, k1, x0, x1);
  return (b < 32) ? x0 : x1;
#endif
}

// ---- positional encoding element ----
static __device__ __forceinline__ float pe_val(int p, int c) {
  const float KC = (float)(-9.210340371976184 / 256.0);
  int j = c >> 1;
  float dv = expf((float)(2*j) * KC);
  float a = (float)p * dv;
  return (c & 1) ? cosf(a) : sinf(a);
}

// ---- per-wave LayerNorm of a 256-float LDS row (call with one full wave) ----
static __device__ __forceinline__ void wave_ln_row(float* row, const float* lw, const float* lb) {
  const int lane = threadIdx.x & 63;
  float x0 = row[lane], x1 = row[lane+64], x2 = row[lane+128], x3 = row[lane+192];
  float s = (x0 + x1) + (x2 + x3);
#pragma unroll
  for (int m = 1; m < 64; m <<= 1) s += __shfl_xor(s, m);
  float mean = s * 0.00390625f;
  float d0 = x0-mean, d1 = x1-mean, d2 = x2-mean, d3 = x3-mean;
  float q = (d0*d0 + d1*d1) + (d2*d2 + d3*d3);
#pragma unroll
  for (int m = 1; m < 64; m <<= 1) q += __shfl_xor(q, m);
  float rs = 1.0f / sqrtf(q * 0.00390625f + 1e-5f);
  row[lane]     = d0*rs*lw[lane]     + lb[lane];
  row[lane+64]  = d1*rs*lw[lane+64]  + lb[lane+64];
  row[lane+128] = d2*rs*lw[lane+128] + lb[lane+128];
  row[lane+192] = d3*rs*lw[lane+192] + lb[lane+192];
}

// ---- transposed coalesced matvec partials: wt is [K][C] (k-major), x in LDS ----
// 32-deep load batches; a sched_barrier(0) pins all 32 global loads ABOVE the
// consume loop so the compiler cannot re-sink them (round-3 lesson: without it,
// VGPR stayed 112 and MLP ~2). Consumption strictly ascending k with the same
// xv-component/FMA pairing -> per-output accumulation is bitwise identical.
template<int C, int KS, int K>
static __device__ void matvec_t(const float* __restrict__ wt, const float* __restrict__ x,
                                float* __restrict__ part) {
  const int t = threadIdx.x;
  constexpr int O4 = C/4;
  constexpr int KC = K/KS;
  constexpr int BT = (KC < 32) ? KC : 32;
  if (t < O4*KS) {
    const int kc = t / O4, o4 = t - kc*O4;
    const int k0 = kc*KC;
    float4 acc = {0.f,0.f,0.f,0.f};
    const float* wp = wt + k0*C + o4*4;
    for (int kb = 0; kb < KC; kb += BT) {
      float4 w[BT];
#pragma unroll
      for (int j = 0; j < BT; j++) w[j] = *(const float4*)(wp + (kb + j)*C);
      __builtin_amdgcn_sched_barrier(0);
#pragma unroll
      for (int j4 = 0; j4 < BT/4; j4++) {
        float4 xv = *(const float4*)(x + k0 + kb + j4*4);
        float4 a0 = w[j4*4+0], a1 = w[j4*4+1], a2 = w[j4*4+2], a3 = w[j4*4+3];
        acc.x += xv.x*a0.x; acc.y += xv.x*a0.y; acc.z += xv.x*a0.z; acc.w += xv.x*a0.w;
        acc.x += xv.y*a1.x; acc.y += xv.y*a1.y; acc.z += xv.y*a1.z; acc.w += xv.y*a1.w;
        acc.x += xv.z*a2.x; acc.y += xv.z*a2.y; acc.z += xv.z*a2.z; acc.w += xv.z*a2.w;
        acc.x += xv.w*a3.x; acc.y += xv.w*a3.y; acc.z += xv.w*a3.z; acc.w += xv.w*a3.w;
      }
    }
    *(float4*)(part + kc*C + o4*4) = acc;
  }
  __syncthreads();
}

// ---- encoder tiled GEMM stage (unchanged) ----
static __device__ void gemm_stage(const float* __restrict__ A, const float* __restrict__ W,
                                  const float* __restrict__ bias, const float* __restrict__ res,
                                  float* __restrict__ out, int R, int C, int K, int relu,
                                  float* sA) {
  const int t = threadIdx.x;
  const bool act = (t < 256);
  const int lane = t & 63, wv = (t >> 6) & 3;
  const int ntc = C >> 6;
  const int ntiles = (R >> 5) * ntc;
  for (int tile = blockIdx.x; tile < ntiles; tile += gridDim.x) {
    const int tr = tile / ntc, tc = tile - tr*ntc;
    const int r0 = tr << 5;
    const int c  = (tc << 6) + lane;
    float acc[8] = {0,0,0,0,0,0,0,0};
    for (int kc = 0; kc < K; kc += 256) {
      __syncthreads();
      if (act) {
#pragma unroll
        for (int u = 0; u < 8; u++) {
          int idx = u*256 + t;
          int rr = idx >> 6, cc = idx & 63;
          ((float4*)sA)[idx] = *(const float4*)(A + (r0+rr)*K + kc + cc*4);
        }
      }
      __syncthreads();
      if (act) {
        const float* wr = W + c*K + kc;
        for (int k = 0; k < 256; k += 4) {
          float4 w4 = *(const float4*)(wr + k);
#pragma unroll
          for (int r = 0; r < 8; r++) {
            float4 a4 = *(const float4*)(sA + (wv*8 + r)*256 + k);
            acc[r] += a4.x*w4.x; acc[r] += a4.y*w4.y; acc[r] += a4.z*w4.z; acc[r] += a4.w*w4.w;
          }
        }
      }
    }
    if (act) {
      float bb = bias ? bias[c] : 0.0f;
#pragma unroll
      for (int r = 0; r < 8; r++) {
        int row = r0 + wv*8 + r;
        float v = acc[r] + bb;
        if (relu) v = fmaxf(v, 0.0f);
        if (res)  v += res[row*C + c];
        out[row*C + c] = v;
      }
    }
  }
}

// ---- encoder LN stage ----
static __device__ void ln_stage(const float* in, const float* lw, const float* lb,
                                float* out, int R) {
  const int lane = threadIdx.x & 63;
  int gw = blockIdx.x*8 + (threadIdx.x >> 6);
  for (int row = gw; row < R; row += gridDim.x*8) {
    const float* ir = in + row*256;
    float x0 = ir[lane], x1 = ir[lane+64], x2 = ir[lane+128], x3 = ir[lane+192];
    float s = (x0 + x1) + (x2 + x3);
#pragma unroll
    for (int m = 1; m < 64; m <<= 1) s += __shfl_xor(s, m);
    float mean = s * 0.00390625f;
    float d0 = x0-mean, d1 = x1-mean, d2 = x2-mean, d3 = x3-mean;
    float q = (d0*d0 + d1*d1) + (d2*d2 + d3*d3);
#pragma unroll
    for (int m = 1; m < 64; m <<= 1) q += __shfl_xor(q, m);
    float rs = 1.0f / sqrtf(q * 0.00390625f + 1e-5f);
    float* orow = out + row*256;
    orow[lane]     = d0*rs*lw[lane]     + lb[lane];
    orow[lane+64]  = d1*rs*lw[lane+64]  + lb[lane+64];
    orow[lane+128] = d2*rs*lw[lane+128] + lb[lane+128];
    orow[lane+192] = d3*rs*lw[lane+192] + lb[lane+192];
  }
}

// ---- encoder attention core (unchanged; K rows in [p][d] layout) ----
static __device__ void attn_core(const float* qd, const float* kb, const float* vb,
                                 int krstride, int kstride, int nk,
                                 float* sc, float* red, float* ao) {
  const int t = threadIdx.x;
  const int r = t >> 5, p0 = t & 31;
  const bool act = (t < 256);
  if (act) {
#pragma unroll
    for (int pass = 0; pass < 2; pass++) {
      int p = pass*32 + p0;
      if (p < nk) {
        const float4* k4 = (const float4*)(kb + r*krstride + p*kstride);
        const float4* q4 = (const float4*)(qd + r*32);
        float a = 0.0f;
#pragma unroll
        for (int d4 = 0; d4 < 8; d4++) {
          float4 kv = k4[d4], qv = q4[d4];
          a += qv.x*kv.x; a += qv.y*kv.y; a += qv.z*kv.z; a += qv.w*kv.w;
        }
        sc[r*48 + p] = a * 0.17677669529663687f;
      }
    }
  }
  __syncthreads();
  if (t < 8) {
    float m = sc[t*48];
    for (int p = 1; p < nk; p++) m = fmaxf(m, sc[t*48 + p]);
    red[t] = m;
  }
  __syncthreads();
  if (act) {
#pragma unroll
    for (int pass = 0; pass < 2; pass++) {
      int p = pass*32 + p0;
      if (p < nk) sc[r*48 + p] = expf(sc[r*48 + p] - red[r]);
    }
  }
  __syncthreads();
  if (t < 8) {
    float s = 0.0f;
    for (int p = 0; p < nk; p++) s += sc[t*48 + p];
    red[8 + t] = s;
  }
  __syncthreads();
  if (act) {
#pragma unroll
    for (int pass = 0; pass < 2; pass++) {
      int p = pass*32 + p0;
      if (p < nk) sc[r*48 + p] = sc[r*48 + p] / red[8 + r];
    }
  }
  __syncthreads();
  if (act) {
    const int d2 = t & 31;
    const float* vr = vb + r*krstride + d2;
    float a = 0.0f;
    for (int p = 0; p < nk; p++) a += sc[r*48 + p] * vr[p*kstride];
    ao[r*32 + d2] = a;
  }
  __syncthreads();
}

static __device__ void enc_attn_stage(const float* QKV, float* AO, float* sm) {
  const int t = threadIdx.x;
  const bool act = (t < 256);
  float* qd  = sm;
  float* sc  = sm + 256;
  float* ao  = sm + 640;
  float* red = sm + 896;
  for (int pi = blockIdx.x; pi < 512; pi += gridDim.x) {
    int b = pi >> 3, h = pi & 7;
    const float* Qb = QKV + b*48*768 + h*32;
    const float* Kb = QKV + b*48*768 + 256 + h*32;
    const float* Vb = QKV + b*48*768 + 512 + h*32;
    for (int qg = 0; qg < 6; qg++) {
      if (act) { int r = t >> 5, d2 = t & 31; qd[r*32 + d2] = Qb[(qg*8 + r)*768 + d2]; }
      __syncthreads();
      attn_core(qd, Kb, Vb, 0, 768, 48, sc, red, ao);
      if (act) { int r = t >> 5, d2 = t & 31; AO[(b*48 + qg*8 + r)*256 + h*32 + d2] = ao[r*32 + d2]; }
      __syncthreads();
    }
  }
}

// ---- decode attention: K transposed [d4][p][4] (coalesced over p); V in [p][d] ----
// QK batch-loads all 8 K-float4s then sched_barrier pins them above the dot;
// PV batch-loads 8 V rows the same way. Accumulation order unchanged.
static __device__ void attn_dec(const float* qd, const float* kt, const float* v,
                                int nk, float* sc, float* red, float* ao) {
  const int t = threadIdx.x;
  const int r = t >> 5, p0 = t & 31;
  const bool act = (t < 256);
  if (act) {
    const float4* q4 = (const float4*)(qd + r*32);
#pragma unroll
    for (int pass = 0; pass < 2; pass++) {
      int p = pass*32 + p0;
      if (p < nk) {
        const float* kb = kt + r*1536 + p*4;   // r = head; 8 d4-blocks of 192 floats
        float4 kv[8];
#pragma unroll
        for (int j = 0; j < 8; j++) kv[j] = *(const float4*)(kb + j*192);
        __builtin_amdgcn_sched_barrier(0);
        float a = 0.0f;
#pragma unroll
        for (int j = 0; j < 8; j++) {
          float4 qv = q4[j];
          a += qv.x*kv[j].x; a += qv.y*kv[j].y; a += qv.z*kv[j].z; a += qv.w*kv[j].w;
        }
        sc[r*48 + p] = a * 0.17677669529663687f;
      }
    }
  }
  __syncthreads();
  if (t < 8) {
    const float* scr = sc + t*48;
    float m = scr[0];
    int p = 1;
    for (; p + 8 <= nk; p += 8) {
      float s0=scr[p],s1=scr[p+1],s2=scr[p+2],s3=scr[p+3],
            s4=scr[p+4],s5=scr[p+5],s6=scr[p+6],s7=scr[p+7];
      m=fmaxf(m,s0); m=fmaxf(m,s1); m=fmaxf(m,s2); m=fmaxf(m,s3);
      m=fmaxf(m,s4); m=fmaxf(m,s5); m=fmaxf(m,s6); m=fmaxf(m,s7);
    }
    for (; p < nk; p++) m = fmaxf(m, scr[p]);
    red[t] = m;
  }
  __syncthreads();
  if (act) {
#pragma unroll
    for (int pass = 0; pass < 2; pass++) {
      int p = pass*32 + p0;
      if (p < nk) sc[r*48 + p] = expf(sc[r*48 + p] - red[r]);
    }
  }
  __syncthreads();
  if (t < 8) {
    const float* scr = sc + t*48;
    float s = 0.0f;
    int p = 0;
    for (; p + 8 <= nk; p += 8) {
      float s0=scr[p],s1=scr[p+1],s2=scr[p+2],s3=scr[p+3],
            s4=scr[p+4],s5=scr[p+5],s6=scr[p+6],s7=scr[p+7];
      s+=s0; s+=s1; s+=s2; s+=s3; s+=s4; s+=s5; s+=s6; s+=s7;
    }
    for (; p < nk; p++) s += scr[p];
    red[8 + t] = s;
  }
  __syncthreads();
  if (act) {
#pragma unroll
    for (int pass = 0; pass < 2; pass++) {
      int p = pass*32 + p0;
      if (p < nk) sc[r*48 + p] = sc[r*48 + p] / red[8 + r];
    }
  }
  __syncthreads();
  if (act) {
    const int d2 = t & 31;
    const float* vr = v + r*32 + d2;
    float a = 0.0f;
    int p = 0;
    for (; p + 8 <= nk; p += 8) {
      float vv[8], ss[8];
#pragma unroll
      for (int j = 0; j < 8; j++) vv[j] = vr[(p+j)*256];
#pragma unroll
      for (int j = 0; j < 8; j++) ss[j] = sc[r*48 + p + j];
      __builtin_amdgcn_sched_barrier(0);
#pragma unroll
      for (int j = 0; j < 8; j++) a += ss[j] * vv[j];
    }
    for (; p < nk; p++) a += sc[r*48 + p] * vr[p*256];
    ao[r*32 + d2] = a;
  }
  __syncthreads();
}

// ================= the single persistent kernel =================
__global__ void __launch_bounds__(512)
genrev7_kernel(GParams P) {
  __shared__ float sm[8448];
  float* ws = P.ws;
  const int wg = blockIdx.x;
  const int t  = threadIdx.x;

  // ---- E0: encoder embeddings + pe ----
  if (t < 256) {
    for (int rr = 0; rr < 12; rr++) {
      int row = wg*12 + rr;
      int b = row / 48, s = row % 48;
      int tok = (s < 32) ? P.xc[b*32 + s] : P.xct[b*16 + (s - 32)];
      ws[X_OFF + row*256 + t] = P.emb[(s*1024 + tok)*256 + t] + pe_val(s, t);
    }
  }
  gbar(&g_cntA, &g_genA, 256);

  // ---- encoder: 6 post-norm layers ----
  float* Xp = ws + X_OFF;
  for (int l = 0; l < 6; l++) {
    gemm_stage(Xp, P.ewqkv + l*768*256, P.ebqkv + l*768, nullptr, ws + QKV_OFF, 3072, 768, 256, 0, sm);
    gbar(&g_cntA, &g_genA, 256);
    enc_attn_stage(ws + QKV_OFF, ws + AO_OFF, sm);
    gbar(&g_cntA, &g_genA, 256);
    gemm_stage(ws + AO_OFF, P.ewo + l*256*256, P.ebo + l*256, Xp, ws + RES1_OFF, 3072, 256, 256, 0, sm);
    gbar(&g_cntA, &g_genA, 256);
    ln_stage(ws + RES1_OFF, P.elnw + (l*2 + 0)*256, P.elnb + (l*2 + 0)*256, ws + X1_OFF, 3072);
    gbar(&g_cntA, &g_genA, 256);
    gemm_stage(ws + X1_OFF, P.ew1 + l*1024*256, P.eb1 + l*1024, nullptr, ws + HB_OFF, 3072, 1024, 256, 1, sm);
    gbar(&g_cntA, &g_genA, 256);
    gemm_stage(ws + HB_OFF, P.ew2 + l*256*1024, P.eb2 + l*256, ws + X1_OFF, ws + RES2_OFF, 3072, 256, 1024, 0, sm);
    gbar(&g_cntA, &g_genA, 256);
    ln_stage(ws + RES2_OFF, P.elnw + (l*2 + 1)*256, P.elnb + (l*2 + 1)*256, Xp, 3072);
    gbar(&g_cntA, &g_genA, 256);
  }
  ln_stage(Xp, P.lnfw, P.lnfb, ws + MEM_OFF, 3072);
  gbar(&g_cntA, &g_genA, 256);
  // cross K (plain, temp at PCK) and cross V (final layout) for all 6 layers
  for (int l = 0; l < 6; l++) {
    gemm_stage(ws + MEM_OFF, P.cwqkv + (l*768 + 256)*256, P.cbqkv + l*768 + 256, nullptr,
               ws + PCK_OFF + l*786432, 3072, 256, 256, 0, sm);
    gemm_stage(ws + MEM_OFF, P.cwqkv + (l*768 + 512)*256, P.cbqkv + l*768 + 512, nullptr,
               ws + CV_OFF + l*786432, 3072, 256, 256, 0, sm);
  }
  gbar(&g_cntA, &g_genA, 256);

  // ---- transpose phase: decode weights -> [k][o]; plain cross-K -> [d4][p][4] ----
  {
    const int gt = wg*512 + t;
    const int GT = 256*512;
    for (int idx = gt; idx < 6*256*768; idx += GT) {
      int l = idx / 196608, r = idx - l*196608;
      int k = r / 768, o = r - k*768;
      ws[SWQKVT + idx] = P.swqkv[(l*768 + o)*256 + k];
    }
    for (int idx = gt; idx < 6*65536; idx += GT) {
      int l = idx >> 16, r = idx & 65535, k = r >> 8, o = r & 255;
      ws[SWOT + idx] = P.swo[(l*256 + o)*256 + k];
    }
    for (int idx = gt; idx < 6*65536; idx += GT) {
      int l = idx >> 16, r = idx & 65535, k = r >> 8, o = r & 255;
      ws[CWQT + idx] = P.cwqkv[(l*768 + o)*256 + k];
    }
    for (int idx = gt; idx < 6*65536; idx += GT) {
      int l = idx >> 16, r = idx & 65535, k = r >> 8, o = r & 255;
      ws[CWOT + idx] = P.cwo[(l*256 + o)*256 + k];
    }
    for (int idx = gt; idx < 6*262144; idx += GT) {
      int l = idx >> 18, r = idx & 262143, k = r >> 10, o = r & 1023;
      ws[DW1T + idx] = P.dw1[(l*1024 + o)*256 + k];
    }
    for (int idx = gt; idx < 6*262144; idx += GT) {
      int l = idx >> 18, r = idx & 262143, k = r >> 8, o = r & 255;
      ws[DW2T + idx] = P.dw2[(l*256 + o)*1024 + k];
    }
    // CKT[l][b][d4][p][c] from plain CK[l][b*48+p][d]
    for (int idx = gt; idx < 6*64*48*256; idx += GT) {
      int l = idx / 786432, r = idx - l*786432;
      int b = r / 12288, q = r - b*12288;
      int d4 = q / 192, s2 = q - d4*192;
      int p = s2 >> 2, c = s2 & 3;
      ws[CKT_OFF + idx] = ws[PCK_OFF + l*786432 + (b*48 + p)*256 + d4*4 + c];
    }
    // zero the cohort soft-sync slots (relaxed atomic stores -> LLC)
    unsigned* ssync = (unsigned*)(ws + SSYNC_OFF);
    for (int idx = gt; idx < 3072; idx += GT)
      __hip_atomic_store(&ssync[idx], 0u, __ATOMIC_RELAXED, __HIP_MEMORY_SCOPE_AGENT);
  }
  gbar(&g_cntA, &g_genA, 256);

  // ================= barrier-free per-row decode: WG b owns batch row b =================
  if (wg >= 64) return;
  const int b = wg;
  const int grp = wg & 7;      // round-robin dispatch: same grp -> same XCD-L2
  unsigned* ssync = (unsigned*)(ws + SSYNC_OFF);

  float* cur  = sm;           // 256
  float* qv   = sm + 256;     // 256
  float* av   = sm + 512;     // 256
  float* y1   = sm + 768;     // 256
  float* y2   = sm + 1024;    // 256
  float* hbf  = sm + 1280;    // 1024
  float* sc   = sm + 2304;    // 384
  float* red  = sm + 2688;    // 32
  float* y0   = sm + 2720;    // 256
  float* bvv  = sm + 2976;    // 256
  int*   bii  = (int*)(sm + 3232); // 256
  float* part = sm + 3488;    // 2048

  if (t < 256) y0[t] = P.sos[t] + pe_val(0, t);
  __syncthreads();

  for (int i = 0; i < 48; i++) {
    if (t < 256) cur[t] = y0[t];
    __syncthreads();
    for (int l = 0; l < 6; l++) {
      // keep the 8 same-XCD WGs inside the same layer window (weight L2 sharing)
      cohort_sync(ssync + (i*7 + l)*8 + grp);
      const int skt = SKT_OFF + l*786432 + b*12288;
      const int sv  = SV_OFF  + l*786432 + b*12288;
      const int ckt = CKT_OFF + l*786432 + b*12288;
      const int cv  = CV_OFF  + l*786432 + b*12288;
      // --- self QKV (transposed, coalesced, 2-way k-split) ---
      matvec_t<768,2,256>(ws + SWQKVT + l*196608, cur, part);
      for (int o = t; o < 768; o += 512) {
        float v = part[o] + part[768 + o] + P.sbqkv[l*768 + o];
        if (o < 256)      qv[o] = v;
        else if (o < 512) { int d = o - 256; ws[skt + (d>>2)*192 + i*4 + (d&3)] = v; }
        else              ws[sv + i*256 + (o - 512)] = v;
      }
      __syncthreads();
      attn_dec(qv, ws + skt, ws + sv, i + 1, sc, red, av);
      // --- self out-proj + residual + LN ---
      matvec_t<256,8,256>(ws + SWOT + l*65536, av, part);
      if (t < 256) {
        float s = part[t];
#pragma unroll
        for (int kc = 1; kc < 8; kc++) s += part[kc*256 + t];
        y1[t] = cur[t] + (s + P.sbo[l*256 + t]);
      }
      __syncthreads();
      if (t < 64) wave_ln_row(y1, P.dlnw + (l*3 + 0)*256, P.dlnb + (l*3 + 0)*256);
      __syncthreads();
      // --- cross q ---
      matvec_t<256,8,256>(ws + CWQT + l*65536, y1, part);
      if (t < 256) {
        float s = part[t];
#pragma unroll
        for (int kc = 1; kc < 8; kc++) s += part[kc*256 + t];
        qv[t] = s + P.cbqkv[l*768 + t];
      }
      __syncthreads();
      attn_dec(qv, ws + ckt, ws + cv, 48, sc, red, av);
      matvec_t<256,8,256>(ws + CWOT + l*65536, av, part);
      if (t < 256) {
        float s = part[t];
#pragma unroll
        for (int kc = 1; kc < 8; kc++) s += part[kc*256 + t];
        y2[t] = y1[t] + (s + P.cbo[l*256 + t]);
      }
      __syncthreads();
      if (t < 64) wave_ln_row(y2, P.dlnw + (l*3 + 1)*256, P.dlnb + (l*3 + 1)*256);
      __syncthreads();
      // --- FFN ---
      matvec_t<1024,2,256>(ws + DW1T + l*262144, y2, part);
      for (int o = t; o < 1024; o += 512)
        hbf[o] = fmaxf(part[o] + part[1024 + o] + P.db1[l*1024 + o], 0.0f);
      __syncthreads();
      matvec_t<256,8,1024>(ws + DW2T + l*262144, hbf, part);
      if (t < 256) {
        float s = part[t];
#pragma unroll
        for (int kc = 1; kc < 8; kc++) s += part[kc*256 + t];
        cur[t] = y2[t] + (s + P.db2[l*256 + t]);
      }
      __syncthreads();
      if (t < 64) wave_ln_row(cur, P.dlnw + (l*3 + 2)*256, P.dlnb + (l*3 + 2)*256);
      __syncthreads();
    }
    // --- final LN (lnf[1]) ---
    if (t < 64) wave_ln_row(cur, P.lnfw + 256, P.lnfb + 256);
    __syncthreads();
    // --- head: wave-cooperative rows; 8 float4 loads batched ahead of the
    //     shfl-reduce chains (sched_barrier pins them) ---
    cohort_sync(ssync + (i*7 + 6)*8 + grp);
    {
      const int wv = t >> 6, lane = t & 63;
      const float4 x4 = *(const float4*)(cur + lane*4);
      for (int base = 0; base < 1024; base += 64) {
        float4 wl[8];
#pragma unroll
        for (int u = 0; u < 4; u++) {
          int o = base + u*16 + wv;
          wl[u*2]   = *(const float4*)(P.hw + (size_t)(i*1024 + o)*256 + lane*4);
          wl[u*2+1] = *(const float4*)(P.hw + (size_t)(i*1024 + o + 8)*256 + lane*4);
        }
        __builtin_amdgcn_sched_barrier(0);
#pragma unroll
        for (int u = 0; u < 4; u++) {
          int o = base + u*16 + wv, o2 = o + 8;
          float4 wa = wl[u*2], wb = wl[u*2+1];
          float sa = wa.x*x4.x; sa += wa.y*x4.y; sa += wa.z*x4.z; sa += wa.w*x4.w;
          float sb = wb.x*x4.x; sb += wb.y*x4.y; sb += wb.z*x4.z; sb += wb.w*x4.w;
#pragma unroll
          for (int m = 1; m < 64; m <<= 1) { sa += __shfl_xor(sa, m); sb += __shfl_xor(sb, m); }
          if (lane == 0) {
            hbf[o]  = sa + P.hb[i*1024 + o];
            hbf[o2] = sb + P.hb[i*1024 + o2];
          }
        }
      }
    }
    __syncthreads();
    for (int o = t; o < 1024; o += 512)
      P.out[3072 + i*65536 + b*1024 + o] = hbf[o];
    __syncthreads();
    // --- gumbel-argmax sampling ---
    unsigned k0, k1;
    step_key(i, k0, k1);
    if (t < 256) {
      float bestv = -INFINITY; int besti = 0;
#pragma unroll
      for (int e = 0; e < 4; e++) {
        int v = t*4 + e;
        unsigned bits = gumbel_bits(k0, k1, b, v);
        float f = __uint_as_float((bits >> 9) | 0x3f800000u);
        float u = fmaxf(f - 1.0f, 1.17549435e-38f);
        float g = -logf(-logf(u));
        float z = g + hbf[v] / 0.1f;
        if (z > bestv) { bestv = z; besti = v; }
      }
      bvv[t] = bestv; bii[t] = besti;
    }
    __syncthreads();
    for (int s = 128; s > 0; s >>= 1) {
      if (t < s) {
        float ov = bvv[t+s]; int oi = bii[t+s];
        if (ov > bvv[t] || (ov == bvv[t] && oi < bii[t])) { bvv[t] = ov; bii[t] = oi; }
      }
      __syncthreads();
    }
    const int ch = bii[0];
    if (t == 0) {
      if (i < 32) P.out[b*32 + i] = (float)ch;
      else        P.out[2048 + b*16 + (i - 32)] = (float)ch;
    }
    if (t < 256) y0[t] = P.emb[(i*1024 + ch)*256 + t] + pe_val(i + 1, t);
    __syncthreads();
  }
}

extern "C" void kernel_launch(void* const* d_in, const int* in_sizes, int n_in,
                              void* d_out, int out_size, void* d_ws, size_t ws_size,
                              hipStream_t stream) {
  (void)in_sizes; (void)n_in; (void)out_size; (void)ws_size;
  GParams p;
  p.xc    = (const int*)  d_in[0];
  p.xct   = (const int*)  d_in[1];
  p.sos   = (const float*)d_in[2];
  p.emb   = (const float*)d_in[3];
  p.hw    = (const float*)d_in[4];
  p.hb    = (const float*)d_in[5];
  p.ewqkv = (const float*)d_in[6];
  p.ebqkv = (const float*)d_in[7];
  p.ewo   = (const float*)d_in[8];
  p.ebo   = (const float*)d_in[9];
  p.ew1   = (const float*)d_in[10];
  p.eb1   = (const float*)d_in[11];
  p.ew2   = (const float*)d_in[12];
  p.eb2   = (const float*)d_in[13];
  p.elnw  = (const float*)d_in[14];
  p.elnb  = (const float*)d_in[15];
  p.swqkv = (const float*)d_in[16];
  p.sbqkv = (const float*)d_in[17];
  p.swo   = (const float*)d_in[18];
  p.sbo   = (const float*)d_in[19];
  p.cwqkv = (const float*)d_in[20];
  p.cbqkv = (const float*)d_in[21];
  p.cwo   = (const float*)d_in[22];
  p.cbo   = (const float*)d_in[23];
  p.dw1   = (const float*)d_in[24];
  p.db1   = (const float*)d_in[25];
  p.dw2   = (const float*)d_in[26];
  p.db2   = (const float*)d_in[27];
  p.dlnw  = (const float*)d_in[28];
  p.dlnb  = (const float*)d_in[29];
  p.lnfw  = (const float*)d_in[30];
  p.lnfb  = (const float*)d_in[31];
  p.out   = (float*)d_out;
  p.ws    = (float*)d_ws;
  hipLaunchKernelGGL(genrev7_kernel, dim3(256), dim3(512), 0, stream, p);
}